// Round 4
// baseline (1214.488 us; speedup 1.0000x reference)
//
#include <hip/hip_runtime.h>

#define NCLS 80
#define TPOINTS 17064
#define GN_EPS 1e-5f

typedef float v4f __attribute__((ext_vector_type(4)));
typedef short v8s __attribute__((ext_vector_type(8)));

__device__ __forceinline__ unsigned short f2bf(float f) {
    unsigned u = __float_as_uint(f);
    unsigned r = (u + 0x7FFFu + ((u >> 16) & 1u)) >> 16;
    return (unsigned short)r;
}
__device__ __forceinline__ float bf2f(unsigned short h) {
    return __uint_as_float(((unsigned)h) << 16);
}
__device__ __forceinline__ void gload16(const unsigned short* g, unsigned short* l) {
    __builtin_amdgcn_global_load_lds(
        (const __attribute__((address_space(1))) unsigned int*)g,
        (__attribute__((address_space(3))) unsigned int*)l, 16, 0, 0);
}
template<int N> __device__ __forceinline__ void vwait() {
    asm volatile("s_waitcnt vmcnt(%0)" :: "n"(N) : "memory");
    __builtin_amdgcn_sched_barrier(0);
}

struct Lv { int t_conv, t_gn, t_prep, t_h5, xo, P2W, PP, HW, W, H, lwW, loff; };
struct Tab { Lv lv[5]; };

// ---------------------------------------------------------------------------
// Implicit-GEMM conv, fused across levels AND branches (z = br*2+n).
// KB-OUTER / TAP-INNER with B-HALO RESIDENT IN LDS: the old tap-driven loop
// re-staged each B window 9x (once per tap); with 64 blocks/XCD the tap
// re-use distance (8 steps ~ 8MB through a 4MB L2) guaranteed L2 misses ->
// 6.6x beyond-L2 amplification (FETCH 265MB vs 40MB unique) and
// latency-exposed staging that NO schedule fixed (r0-r3 all 235us).
// Now: per kb (ci/32 plane), stage the block's whole B halo panel ONCE
// (448 rows x 64B = 28KB, double-buffered, staged a full kb-epoch ahead);
// 9 taps read shifted windows from LDS. B global traffic /9; panel lead
// time ~2000cyc covers HBM-class misses. A tiles (L2-resident weights)
// triple-buffered, 2 taps ahead, exact per-slot counted vmcnt (per-wave
// FIFO bookkeeping; A=2 gloads/wave/tap, B=1 chunk/wave/slot0..6).
// LDS 2x28 + 3x8 = 80KB -> 2 blocks/CU. XOR chunk-swizzle
// (l&3)^((l>>3)&3) == chunk ^ ((row>>1)&3): 64B-stride row reads hit all
// 8 bank-quads -> conflict-free; read swizzle uses full halo row index.
// Tile 128co x 128pos, 4 waves of 64x64.
// TOWER (HEAD=0): bf16 ci-blocked out + fused GN stats. HEAD=1: fp32 out.
// ---------------------------------------------------------------------------
template<int HEAD>
__global__ __launch_bounds__(256) void conv_k(
    const unsigned short* __restrict__ xin, size_t xin_brs,
    const unsigned short* __restrict__ wt, size_t wt_brs, int wrows,
    const float* __restrict__ bias_c, const float* __restrict__ bias_r,
    unsigned short* __restrict__ yout, float* __restrict__ stats, int layer,
    float* __restrict__ out, int CO, int co_out, int relu_cnt,
    Tab tb)
{
    __shared__ __align__(16) unsigned short sA[3 * 128 * 32];   // 3 A tiles (24KB)
    __shared__ __align__(16) unsigned short sB[2 * 448 * 32];   // 2 B halo panels (56KB)
    const int tid = threadIdx.x, lane = tid & 63, wave = tid >> 6;
    const int bx = blockIdx.x, z = blockIdx.z;
    const int n = z & 1, br = z >> 1;
    int L = 0;
    while (L < 4 && bx >= tb.lv[L + 1].t_conv) ++L;
    const Lv lv = tb.lv[L];
    const int pp0 = (bx - lv.t_conv) * 128;
    const int co0 = HEAD ? 0 : blockIdx.y * 128;
    const size_t XELs = 9200640;
    const size_t PP32 = (size_t)lv.PP * 32;

    v4f acc[4][4];
#pragma unroll
    for (int i = 0; i < 4; ++i)
#pragma unroll
        for (int j = 0; j < 4; ++j) acc[i][j] = (v4f)0.f;

    const unsigned short* wtb = wt + (size_t)br * wt_brs;
    const float* bias = br ? bias_r : bias_c;
    const unsigned short* xb = xin + (size_t)br * xin_brs +
                               (size_t)lv.xo + (size_t)n * lv.PP * 256;

    // per-lane staging pattern: lane l -> row lr = l>>2, source chunk
    // lc = (l&3)^((l>>3)&3) (== chunk ^ ((row>>1)&3) since rows per gload
    // start at multiples of 16).
    const int r0 = wave * 32;
    const int lr = lane >> 2;
    const int lc = ((lane & 3) ^ ((lane >> 3) & 3)) * 8;
    const unsigned short* ag = wtb + (size_t)(co0 + r0 + lr) * 32 + lc;
    const unsigned short* bgh = xb + (ptrdiff_t)(pp0 - lv.P2W - 1) * 32 +
                                (ptrdiff_t)(lr * 32 + lc);
    unsigned short* laW = &sA[r0 * 32];
    const size_t wstride2 = (size_t)wrows * 32;   // elems per (tap,kb) A tile

    const int col = lane & 15, q = lane >> 4;
    const int wco = (wave & 1) * 64, wpos = (wave >> 1) * 64;
    const int qs = (q ^ ((col >> 1) & 3)) << 3;
    int ard[4];
#pragma unroll
    for (int i = 0; i < 4; ++i) ard[i] = (wco + i * 16 + col) * 32 + qs;

    auto stageA = [&](int kb_, int tap_, int sel) {
        const unsigned short* at = ag + (size_t)(tap_ * 8 + kb_) * wstride2;
        unsigned short* l = laW + sel * 4096;
        gload16(at,       l);
        gload16(at + 512, l + 512);
    };
    auto stageB = [&](int kb_, int c) {
        const int k = c * 4 + wave;            // 28 chunks of 16 rows
        gload16(bgh + (size_t)kb_ * PP32 + (size_t)k * 512,
                &sB[(kb_ & 1) * 14336 + k * 512]);
    };
    auto computeTap = [&](int kb_, int t, int sel) {
        const int trow = (t / 3) * lv.P2W + (t % 3);
        const unsigned short* bp = &sB[(kb_ & 1) * 14336];
        const unsigned short* ap = &sA[sel * 4096];
        v8s af[4], bfr[4];
#pragma unroll
        for (int i = 0; i < 4; ++i) af[i] = *(const v8s*)&ap[ard[i]];
#pragma unroll
        for (int j = 0; j < 4; ++j) {
            const int r = wpos + j * 16 + col + trow;
            bfr[j] = *(const v8s*)&bp[r * 32 + ((q ^ ((r >> 1) & 3)) << 3)];
        }
#pragma unroll
        for (int i = 0; i < 4; ++i)
#pragma unroll
            for (int j = 0; j < 4; ++j)
                acc[i][j] = __builtin_amdgcn_mfma_f32_16x16x32_bf16(
                    af[i], bfr[j], acc[i][j], 0, 0, 0);
    };

#define TSLOT(T, VN, AKB, ATAP, DOB)                                       \
    stageA(AKB, ATAP, (ATAP) % 3);                                         \
    if (DOB) stageB(kb + 1, T);                                            \
    vwait<VN>();                                                           \
    __builtin_amdgcn_s_barrier();                                          \
    __builtin_amdgcn_sched_barrier(0);                                     \
    computeTap(kb, T, (T) % 3);                                            \
    __builtin_amdgcn_sched_barrier(0);                                     \
    __builtin_amdgcn_s_barrier();

    // prologue: whole B(0) panel + A(0,0), A(0,1)
#pragma unroll
    for (int c = 0; c < 7; ++c) stageB(0, c);
    stageA(0, 0, 0);
    stageA(0, 1, 1);
    vwait<4>();                       // B(0) retired per-wave; A00/A01 in flight
    __builtin_amdgcn_s_barrier();
    __builtin_amdgcn_sched_barrier(0);

#pragma unroll 1
    for (int kb = 0; kb < 7; ++kb) {
        TSLOT(0, 5, kb, 2, true)
        TSLOT(1, 6, kb, 3, true)
        TSLOT(2, 7, kb, 4, true)
        TSLOT(3, 7, kb, 5, true)
        TSLOT(4, 7, kb, 6, true)
        TSLOT(5, 7, kb, 7, true)
        TSLOT(6, 7, kb, 8, true)
        TSLOT(7, 6, kb + 1, 0, false)
        TSLOT(8, 5, kb + 1, 1, false)
        vwait<4>();                   // B(kb+1) fully deposited (per-wave)
        __builtin_amdgcn_s_barrier(); // publish panel to all waves
        __builtin_amdgcn_sched_barrier(0);
    }
    {   // kb = 7: no B staging, no next-kb A prefetch
        const int kb = 7;
#define LSLOTA(T, VN)                                                      \
        stageA(7, (T) + 2, ((T) + 2) % 3);                                 \
        vwait<VN>();                                                       \
        __builtin_amdgcn_s_barrier();                                      \
        __builtin_amdgcn_sched_barrier(0);                                 \
        computeTap(kb, T, (T) % 3);                                        \
        __builtin_amdgcn_sched_barrier(0);                                 \
        __builtin_amdgcn_s_barrier();
        LSLOTA(0, 4)
        LSLOTA(1, 4)
        LSLOTA(2, 4)
        LSLOTA(3, 4)
        LSLOTA(4, 4)
        LSLOTA(5, 4)
        LSLOTA(6, 4)
        // t = 7
        vwait<2>();
        __builtin_amdgcn_s_barrier();
        __builtin_amdgcn_sched_barrier(0);
        computeTap(kb, 7, 7 % 3);
        __builtin_amdgcn_sched_barrier(0);
        __builtin_amdgcn_s_barrier();
        // t = 8
        vwait<0>();
        __builtin_amdgcn_s_barrier();
        __builtin_amdgcn_sched_barrier(0);
        computeTap(kb, 8, 8 % 3);
#undef LSLOTA
    }
#undef TSLOT

    if (!HEAD) {
        unsigned short* yb = yout + (size_t)br * XELs + (size_t)lv.xo +
                             (size_t)n * lv.PP * 256;
        const int slot = br * 3 + layer;
#pragma unroll
        for (int i = 0; i < 4; ++i) {
            const int cobase = co0 + wco + i * 16 + q * 4;
            const float4 b4 = *(const float4*)(bias + cobase);
            const size_t kbo = (size_t)(cobase >> 5) * PP32;
            const int cc = cobase & 31;
            float s = 0.f, ss = 0.f;
#pragma unroll
            for (int j = 0; j < 4; ++j) {
                const int pp = pp0 + wpos + j * 16 + col;
                const unsigned h2 = (unsigned)pp / (unsigned)lv.P2W;
                const unsigned w2 = (unsigned)pp - h2 * lv.P2W;
                const bool in = (h2 >= 1u) & (h2 <= (unsigned)lv.H) &
                                (w2 >= 1u) & (w2 <= (unsigned)lv.W);
                float v0 = acc[i][j][0] + b4.x;
                float v1 = acc[i][j][1] + b4.y;
                float v2 = acc[i][j][2] + b4.z;
                float v3 = acc[i][j][3] + b4.w;
                if (in) {
                    ushort4 pk;
                    pk.x = f2bf(v0); pk.y = f2bf(v1);
                    pk.z = f2bf(v2); pk.w = f2bf(v3);
                    *(ushort4*)(yb + kbo + (size_t)pp * 32 + cc) = pk;
                    s  += v0 + v1 + v2 + v3;
                    ss += v0 * v0 + v1 * v1 + v2 * v2 + v3 * v3;
                }
            }
#pragma unroll
            for (int o = 32; o > 0; o >>= 1) {
                s  += __shfl_down(s, o, 64);
                ss += __shfl_down(ss, o, 64);
            }
            if (lane == 0) {
                const int g = cobase >> 4;
                const int si = (((slot * 5 + L) * 32) + n * 16 + g) * 2;
                atomicAdd(&stats[si + 0], s);
                atomicAdd(&stats[si + 1], ss);
            }
        }
    } else {
#pragma unroll
        for (int i = 0; i < 4; ++i) {
            const int cobase = wco + i * 16 + q * 4;
            float bv[4];
#pragma unroll
            for (int k = 0; k < 4; ++k)
                bv[k] = (cobase + k < CO) ? bias[cobase + k] : 0.f;
#pragma unroll
            for (int j = 0; j < 4; ++j) {
                const int pp = pp0 + wpos + j * 16 + col;
                const unsigned h2 = (unsigned)pp / (unsigned)lv.P2W;
                const unsigned w2 = (unsigned)pp - h2 * lv.P2W;
                const bool in = (h2 >= 1u) & (h2 <= (unsigned)lv.H) &
                                (w2 >= 1u) & (w2 <= (unsigned)lv.W);
                if (in) {
                    const int p = (h2 - 1) * lv.W + (w2 - 1);
                    float* ob = out + ((size_t)n * TPOINTS + lv.loff + p) * 85 + co_out;
#pragma unroll
                    for (int k = 0; k < 4; ++k) {
                        const int co = cobase + k;
                        if (co < CO) {
                            float v = acc[i][j][k] + bv[k];
                            if (co < relu_cnt) v = fmaxf(v, 0.f);
                            ob[co] = v;
                        }
                    }
                }
            }
        }
    }
}

// ---------------------------------------------------------------------------
// Small reg-head (bbox+ctr, CO=5) — ci-blocked addressing.
// ---------------------------------------------------------------------------
__global__ __launch_bounds__(256) void head5_k(
    const unsigned short* __restrict__ xin,
    const unsigned short* __restrict__ wt,
    const float* __restrict__ bias, float* __restrict__ out, Tab tb)
{
    __shared__ unsigned short sA[16 * 32];
    __shared__ unsigned short sB[256 * 32];
    const int tid = threadIdx.x, lane = tid & 63, wave = tid >> 6;
    const int bx = blockIdx.x, n = blockIdx.z;
    int L = 0;
    while (L < 4 && bx >= tb.lv[L + 1].t_h5) ++L;
    const Lv lv = tb.lv[L];
    const int pp0 = (bx - lv.t_h5) * 256;
    const size_t PP32 = (size_t)lv.PP * 32;

    v4f acc[4];
#pragma unroll
    for (int j = 0; j < 4; ++j) acc[j] = (v4f)0.f;

    const unsigned short* xb = xin + (size_t)lv.xo + (size_t)n * lv.PP * 256;
    const unsigned short* brow = xb + (size_t)(pp0 + tid) * 32;
    const int bs = (tid >> 1) & 3;
    int bw[4];
#pragma unroll
    for (int c = 0; c < 4; ++c) bw[c] = tid * 32 + ((c ^ bs) << 3);

    const int col = lane & 15, q = lane >> 4;
    const int qs = (q ^ ((col >> 1) & 3)) << 3;
    const int ard = col * 32 + qs;
    const int wb = wave * 64;
    int brd[4];
#pragma unroll
    for (int j = 0; j < 4; ++j) brd[j] = (wb + j * 16 + col) * 32 + qs;

    for (int step = 0; step < 72; ++step) {
        const int t = step >> 3, kb = step & 7;
        const ptrdiff_t off = ((ptrdiff_t)(t / 3) - 1) * lv.P2W + (t % 3) - 1;
        const unsigned short* bt = brow + (size_t)kb * PP32 + off * 32;
        uint4 bv[4];
#pragma unroll
        for (int c = 0; c < 4; ++c) bv[c] = *(const uint4*)(bt + c * 8);
        uint4 av[4];
        if (tid < 16) {
            const unsigned short* at = wt + (size_t)((step) * 16 + tid) * 32;
#pragma unroll
            for (int c = 0; c < 4; ++c) av[c] = *(const uint4*)(at + c * 8);
        }
        __syncthreads();
#pragma unroll
        for (int c = 0; c < 4; ++c) *(uint4*)&sB[bw[c]] = bv[c];
        if (tid < 16) {
#pragma unroll
            for (int c = 0; c < 4; ++c) *(uint4*)&sA[bw[c]] = av[c];
        }
        __syncthreads();
        v8s af = *(const v8s*)&sA[ard];
        v8s bfr[4];
#pragma unroll
        for (int j = 0; j < 4; ++j) bfr[j] = *(const v8s*)&sB[brd[j]];
#pragma unroll
        for (int j = 0; j < 4; ++j)
            acc[j] = __builtin_amdgcn_mfma_f32_16x16x32_bf16(
                af, bfr[j], acc[j], 0, 0, 0);
    }

    float bv4[4];
#pragma unroll
    for (int k = 0; k < 4; ++k) {
        const int co = q * 4 + k;
        bv4[k] = (co < 5) ? bias[co] : 0.f;
    }
#pragma unroll
    for (int j = 0; j < 4; ++j) {
        const int pp = pp0 + wb + j * 16 + col;
        const unsigned h2 = (unsigned)pp / (unsigned)lv.P2W;
        const unsigned w2 = (unsigned)pp - h2 * lv.P2W;
        const bool in = (h2 >= 1u) & (h2 <= (unsigned)lv.H) &
                        (w2 >= 1u) & (w2 <= (unsigned)lv.W);
        if (in) {
            const int p = (h2 - 1) * lv.W + (w2 - 1);
            float* ob = out + ((size_t)n * TPOINTS + lv.loff + p) * 85 + 80;
#pragma unroll
            for (int k = 0; k < 4; ++k) {
                const int co = q * 4 + k;
                if (co < 5) {
                    float v = acc[j][k] + bv4[k];
                    if (co < 4) v = fmaxf(v, 0.f);
                    ob[co] = v;
                }
            }
        }
    }
}

// ---------------------------------------------------------------------------
// GN + affine + ReLU, in-place, fused across levels AND branches (z=br*2+n).
// ci-blocked layout: thread (tid&7) owns one kb-plane chunk of 32 ch.
// ---------------------------------------------------------------------------
__global__ __launch_bounds__(256) void gn_k(
    unsigned short* __restrict__ x, const float* __restrict__ stats, int layer,
    const float* __restrict__ g_c, const float* __restrict__ be_c,
    const float* __restrict__ g_r, const float* __restrict__ be_r, Tab tb)
{
    const int tid = threadIdx.x, bx = blockIdx.x, z = blockIdx.z;
    const int n = z & 1, br = z >> 1;
    const size_t XELs = 9200640;
    int L = 0;
    while (L < 4 && bx >= tb.lv[L + 1].t_gn) ++L;
    const Lv lv = tb.lv[L];
    const int pos = (bx - lv.t_gn) * 32 + (tid >> 3);
    if (pos >= lv.HW) return;
    const int slot = br * 3 + layer;
    const float* gamma = (br ? g_r : g_c) + layer * 256;
    const float* beta  = (br ? be_r : be_c) + layer * 256;
    const int c0 = (tid & 7) * 32;
    const int h = pos >> lv.lwW, w = pos & (lv.W - 1);
    const int pp = (h + 1) * lv.P2W + (w + 1);
    unsigned short* p = x + (size_t)br * XELs + (size_t)lv.xo +
                        (size_t)n * lv.PP * 256 +
                        (size_t)(tid & 7) * lv.PP * 32 + (size_t)pp * 32;
    const float inv = 1.0f / (16.0f * (float)lv.HW);
    const int sb = ((slot * 5 + L) * 32 + n * 16) * 2;

    float scv[32], shv[32];
#pragma unroll
    for (int gg = 0; gg < 2; ++gg) {
        const int g = (c0 >> 4) + gg;
        const float m = stats[sb + g * 2 + 0] * inv;
        const float v = stats[sb + g * 2 + 1] * inv - m * m;
        const float rs = rsqrtf(v + GN_EPS);
#pragma unroll
        for (int k = 0; k < 16; ++k) {
            const int c = g * 16 + k;
            const float sc = rs * gamma[c];
            scv[gg * 16 + k] = sc;
            shv[gg * 16 + k] = beta[c] - m * sc;
        }
    }
#pragma unroll
    for (int u = 0; u < 4; ++u) {
        uint4 a = *(const uint4*)(p + u * 8);
        unsigned wds[4] = {a.x, a.y, a.z, a.w};
#pragma unroll
        for (int k = 0; k < 4; ++k) {
            const int e = u * 8 + k * 2;
            float lo = bf2f((unsigned short)(wds[k] & 0xffffu));
            float hi = bf2f((unsigned short)(wds[k] >> 16));
            lo = fmaxf(lo * scv[e]     + shv[e],     0.f);
            hi = fmaxf(hi * scv[e + 1] + shv[e + 1], 0.f);
            wds[k] = (unsigned)f2bf(lo) | ((unsigned)f2bf(hi) << 16);
        }
        uint4 o; o.x = wds[0]; o.y = wds[1]; o.z = wds[2]; o.w = wds[3];
        *(uint4*)(p + u * 8) = o;
    }
}

// ---------------------------------------------------------------------------
// fp32 NCHW feats -> bf16 ci-blocked padded interior.
// ---------------------------------------------------------------------------
__global__ __launch_bounds__(256) void prepx_k(
    const float* f0, const float* f1, const float* f2, const float* f3,
    const float* f4, unsigned short* __restrict__ xo, Tab tb)
{
    const float* fs[5] = {f0, f1, f2, f3, f4};
    const int tid = threadIdx.x, bx = blockIdx.x, n = blockIdx.z;
    int L = 0;
    while (L < 4 && bx >= tb.lv[L + 1].t_prep) ++L;
    const Lv lv = tb.lv[L];
    const int pos = (bx - lv.t_prep) * 64 + (tid & 63);
    const int wave = tid >> 6;
    if (pos >= lv.HW) return;
    const int h = pos >> lv.lwW, w = pos & (lv.W - 1);
    const int pp = (h + 1) * lv.P2W + (w + 1);
    const float* src = fs[L] + (size_t)n * 256 * lv.HW + pos;
    unsigned short* dst = xo + (size_t)lv.xo + (size_t)n * lv.PP * 256;
#pragma unroll
    for (int k = 0; k < 16; ++k) {
        const int c = wave * 64 + k * 4;
        ushort4 pk;
        pk.x = f2bf(src[(size_t)(c + 0) * lv.HW]);
        pk.y = f2bf(src[(size_t)(c + 1) * lv.HW]);
        pk.z = f2bf(src[(size_t)(c + 2) * lv.HW]);
        pk.w = f2bf(src[(size_t)(c + 3) * lv.HW]);
        *(ushort4*)(dst + (size_t)(c >> 5) * lv.PP * 32 +
                    (size_t)pp * 32 + (c & 31)) = pk;
    }
}

// ---------------------------------------------------------------------------
// tower weights: [br][layer][tap][kb][co 256][32ci] (per-step tile contiguous)
__global__ __launch_bounds__(256) void prepwt_k(
    const float* __restrict__ cw, const float* __restrict__ rw,
    unsigned short* __restrict__ dst)
{
    const int idx = blockIdx.x * 256 + threadIdx.x;   // 54*65536
    const int ci = idx & 255, co = (idx >> 8) & 255, r = idx >> 16;
    const int tap = r % 9, layer = (r / 9) % 3, br = r / 27;
    const float* s = br ? rw : cw;
    dst[(size_t)r * 65536 + (size_t)(((ci >> 5) * 256 + co) * 32) + (ci & 31)] =
        f2bf(s[(((size_t)layer * 256 + co) * 256 + ci) * 9 + tap]);
}

// head weights: [tap][kb][co rows][32ci]
__global__ __launch_bounds__(256) void prepwh_k(
    const float* __restrict__ src, unsigned short* __restrict__ dst,
    int CO, int rows, int roff)
{
    const int idx = blockIdx.x * 256 + threadIdx.x;
    if (idx >= CO * 2304) return;
    const int ci = idx & 255, rr = idx >> 8;
    const int tap = rr % 9, co = rr / 9;
    dst[((size_t)(tap * 8 + (ci >> 5)) * rows + roff + co) * 32 + (ci & 31)] =
        f2bf(src[((size_t)co * 256 + ci) * 9 + tap]);
}

// ---------------------------------------------------------------------------
extern "C" void kernel_launch(void* const* d_in, const int* in_sizes, int n_in,
                              void* d_out, int out_size, void* d_ws, size_t ws_size,
                              hipStream_t stream) {
    const float* f0 = (const float*)d_in[0];
    const float* f1 = (const float*)d_in[1];
    const float* f2 = (const float*)d_in[2];
    const float* f3 = (const float*)d_in[3];
    const float* f4 = (const float*)d_in[4];
    const float* cls_w  = (const float*)d_in[5];
    const float* cls_b  = (const float*)d_in[6];
    const float* cls_g  = (const float*)d_in[7];
    const float* cls_be = (const float*)d_in[8];
    const float* log_w  = (const float*)d_in[9];
    const float* log_b  = (const float*)d_in[10];
    const float* reg_w  = (const float*)d_in[11];
    const float* reg_b  = (const float*)d_in[12];
    const float* reg_g  = (const float*)d_in[13];
    const float* reg_be = (const float*)d_in[14];
    const float* bbox_w = (const float*)d_in[15];
    const float* bbox_b = (const float*)d_in[16];
    const float* ctr_w  = (const float*)d_in[17];
    const float* ctr_b  = (const float*)d_in[18];
    float* out = (float*)d_out;

    Tab tb;
    //            t_conv t_gn t_prep t_h5 xo       P2W  PP     HW     W    H   lwW loff
    tb.lv[0] = {   0,    0,    0,    0,   0,       130, 13260, 12800, 128, 100, 7, 0     };
    tb.lv[1] = { 104,  400,  200,  52,  6789120,    66,  3432,  3200,  64,  50, 6, 12800 };
    tb.lv[2] = { 131,  500,  250,  66,  8546304,    34,   918,   800,  32,  25, 5, 16000 };
    tb.lv[3] = { 139,  525,  263,  70,  9016320,    18,   270,   208,  16,  13, 4, 16800 };
    tb.lv[4] = { 142,  532,  267,  72,  9154560,    10,    90,    56,   8,   7, 3, 17008 };
    const int NT_CONV = 143, NT_GN = 534, NT_PREP = 268, NT_H5 = 73;
    const size_t XEL = 9200640;

    char* base = (char*)d_ws;
    size_t o = 0;
    auto take = [&](size_t bytes) {
        char* p = base + o; o += (bytes + 255) & ~(size_t)255; return p;
    };
    take(131072);                                        // guard 128KB
    unsigned short* PX = (unsigned short*)take(XEL * 2);          // shared input
    take(131072);
    unsigned short* B1 = (unsigned short*)take(XEL * 2 * 2);      // [br]
    take(131072);
    unsigned short* B2 = (unsigned short*)take(XEL * 2 * 2);      // [br]
    take(131072);
    unsigned short* WT  = (unsigned short*)take((size_t)54 * 65536 * 2);
    unsigned short* WHC = (unsigned short*)take((size_t)9 * 128 * 256 * 2);
    unsigned short* WHR = (unsigned short*)take((size_t)9 * 16 * 256 * 2);
    float* ST  = (float*)take(1920 * 4);
    float* RB5 = (float*)take(32);

    hipMemsetAsync(PX, 0, XEL * 2, stream);
    hipMemsetAsync(B1, 0, XEL * 4, stream);
    hipMemsetAsync(B2, 0, XEL * 4, stream);
    hipMemsetAsync(ST, 0, 1920 * 4, stream);
    hipMemsetAsync(WHR, 0, (size_t)9 * 16 * 256 * 2, stream);
    hipMemcpyAsync(RB5,     bbox_b, 4 * 4, hipMemcpyDeviceToDevice, stream);
    hipMemcpyAsync(RB5 + 4, ctr_b,  1 * 4, hipMemcpyDeviceToDevice, stream);

    prepwt_k<<<dim3(13824), dim3(256), 0, stream>>>(cls_w, reg_w, WT);
    prepwh_k<<<dim3(720), dim3(256), 0, stream>>>(log_w,  WHC, 80, 128, 0);
    prepwh_k<<<dim3(36),  dim3(256), 0, stream>>>(bbox_w, WHR, 4, 16, 0);
    prepwh_k<<<dim3(9),   dim3(256), 0, stream>>>(ctr_w,  WHR, 1, 16, 4);

    const dim3 blk(256);
    prepx_k<<<dim3(NT_PREP, 1, 2), blk, 0, stream>>>(f0, f1, f2, f3, f4, PX, tb);

    // chain: conv0 PX->B1[br], gn0 B1; conv1 B1->B2, gn1 B2; conv2 B2->B1,
    // gn2 B1; cls-head B1[0]; reg-head5 B1[1].
    const size_t WBRS = (size_t)27 * 65536;
    unsigned short* cin[3]  = {PX, B1, B2};
    size_t          cbrs[3] = {0, XEL, XEL};
    unsigned short* cout_[3] = {B1, B2, B1};
    for (int i = 0; i < 3; ++i) {
        conv_k<0><<<dim3(NT_CONV, 2, 4), blk, 0, stream>>>(
            cin[i], cbrs[i], WT + (size_t)i * 9 * 65536, WBRS, 256,
            cls_b + i * 256, reg_b + i * 256,
            cout_[i], ST, i, nullptr, 0, 0, 0, tb);
        gn_k<<<dim3(NT_GN, 1, 4), blk, 0, stream>>>(
            cout_[i], ST, i, cls_g, cls_be, reg_g, reg_be, tb);
    }
    conv_k<1><<<dim3(NT_CONV, 1, 2), blk, 0, stream>>>(
        B1, 0, WHC, 0, 128, log_b, log_b,
        nullptr, nullptr, 0, out, NCLS, 0, 0, tb);
    head5_k<<<dim3(NT_H5, 1, 2), blk, 0, stream>>>(
        B1 + XEL, WHR, RB5, out, tb);
}

// Round 5
// 1145.723 us; speedup vs baseline: 1.0600x; 1.0600x over previous
//
#include <hip/hip_runtime.h>

#define NCLS 80
#define TPOINTS 17064
#define GN_EPS 1e-5f

typedef float v4f __attribute__((ext_vector_type(4)));
typedef short v8s __attribute__((ext_vector_type(8)));

__device__ __forceinline__ unsigned short f2bf(float f) {
    unsigned u = __float_as_uint(f);
    unsigned r = (u + 0x7FFFu + ((u >> 16) & 1u)) >> 16;
    return (unsigned short)r;
}
__device__ __forceinline__ float bf2f(unsigned short h) {
    return __uint_as_float(((unsigned)h) << 16);
}
__device__ __forceinline__ void gload16(const unsigned short* g, unsigned short* l) {
    __builtin_amdgcn_global_load_lds(
        (const __attribute__((address_space(1))) unsigned int*)g,
        (__attribute__((address_space(3))) unsigned int*)l, 16, 0, 0);
}
template<int N> __device__ __forceinline__ void vwait() {
    asm volatile("s_waitcnt vmcnt(%0)" :: "n"(N) : "memory");
    __builtin_amdgcn_sched_barrier(0);
}
#define LGKM0 do { asm volatile("s_waitcnt lgkmcnt(0)" ::: "memory"); \
                   __builtin_amdgcn_sched_barrier(0); } while (0)

struct Lv { int t_conv, t_gn, t_prep, t_h5, xo, P2W, PP, HW, W, H, lwW, loff; };
struct Tab { Lv lv[5]; };

// ---------------------------------------------------------------------------
// Implicit-GEMM conv in the m201 256^2 / 8-wave / deep-pipeline structure.
// r0-r4 showed 4-wave 256-thr blocks are stuck at ~236us regardless of
// schedule/traffic/occupancy: block-wide barriers gang 4 waves (1/SIMD) and
// ~2 blocks/CU can't fill the stalls. m201's structure fixes this INSIDE the
// block: 512 thr / 8 waves (2Mx4N, 128x64 per wave), K-half = one (tap,kb)
// 32-step; 4 rotating 32KB half-buffers (128KB LDS, 1 block/CU); halves
// staged 3 AHEAD (lead ~ full half >= HBM latency) with one vmcnt(8) per
// half (12 in flight, each wave retires its own 4; symmetric counts +
// barrier => buffer collectively complete); raw s_barrier (no drain);
// mid-half barrier for phase split; lgkmcnt(0)+sched_barrier before each
// MFMA cluster (rule 18); setprio(1) around MFMA (T5, now phase-split).
// XOR chunk-swizzle (l&3)^((l>>3)&3) deposit / q^((col>>1)&3) read: 0 bank
// conflicts (measured r0-r4). acc[8][4]=128 VGPR, launch_bounds(512,2).
// Tap shift folded into B staging (per-half goff), as r0-r3.
// TOWER (HEAD=0): bf16 ci-blocked out + fused GN stats. HEAD=1: fp32 out.
// ---------------------------------------------------------------------------
template<int HEAD>
__global__ __launch_bounds__(512, 2) void conv_k(
    const unsigned short* __restrict__ xin, size_t xin_brs,
    const unsigned short* __restrict__ wt, size_t wt_brs, int wrows,
    const float* __restrict__ bias_c, const float* __restrict__ bias_r,
    unsigned short* __restrict__ yout, float* __restrict__ stats, int layer,
    float* __restrict__ out, int CO, int co_out, int relu_cnt,
    Tab tb)
{
    __shared__ __align__(16) unsigned short sA[4 * 256 * 32];   // 64KB
    __shared__ __align__(16) unsigned short sB[4 * 256 * 32];   // 64KB
    const int tid = threadIdx.x, lane = tid & 63, wave = tid >> 6;
    const int bx = blockIdx.x, z = blockIdx.z;
    const int n = z & 1, br = z >> 1;
    int L = 0;
    while (L < 4 && bx >= tb.lv[L + 1].t_h5) ++L;
    const Lv lv = tb.lv[L];
    const int pp0 = (bx - lv.t_h5) * 256;
    const size_t XELs = 9200640;
    const size_t PP32 = (size_t)lv.PP * 32;

    v4f acc[8][4];
#pragma unroll
    for (int i = 0; i < 8; ++i)
#pragma unroll
        for (int j = 0; j < 4; ++j) acc[i][j] = (v4f)0.f;

    const unsigned short* wtb = wt + (size_t)br * wt_brs;
    const float* bias = br ? bias_r : bias_c;
    const unsigned short* xb = xin + (size_t)br * xin_brs +
                               (size_t)lv.xo + (size_t)n * lv.PP * 256;

    // staging: wave w covers rows [w*32, w*32+32) of each 256x32 half-tile
    // (8 waves x 32 = 256 rows). lane l -> row lr = l>>2, source chunk
    // (l&3)^((l>>3)&3): LDS holds row-XOR-swizzled chunks, deposit linear.
    const int r0 = wave * 32;
    const int lr = lane >> 2;
    const int lc = ((lane & 3) ^ ((lane >> 3) & 3)) * 8;
    const unsigned short* ag = wtb + (size_t)(r0 + lr) * 32 + lc;
    const unsigned short* bgh = xb + (ptrdiff_t)(pp0 + r0 + lr) * 32 + lc;
    unsigned short* laW = &sA[r0 * 32];
    unsigned short* lbW = &sB[r0 * 32];
    const size_t wstride2 = (size_t)wrows * 32;   // 8192: elems per K-half tile

    const int col = lane & 15, q = lane >> 4;
    const int m = wave & 1, nn = wave >> 1;       // 2 co-halves x 4 pos-quads
    const int qs = (q ^ ((col >> 1) & 3)) << 3;
    int ard[8], brd[4];
#pragma unroll
    for (int i = 0; i < 8; ++i) ard[i] = (m * 128 + i * 16 + col) * 32 + qs;
#pragma unroll
    for (int j = 0; j < 4; ++j) brd[j] = (nn * 64 + j * 16 + col) * 32 + qs;

    auto stageA2 = [&](int s) {
        const int slot = s & 3;
        const unsigned short* at = ag + (size_t)s * wstride2;
        gload16(at,       laW + slot * 8192);
        gload16(at + 512, laW + slot * 8192 + 512);
    };
    auto stageB2 = [&](int s) {
        const int slot = s & 3;
        const int t = s >> 3, kb = s & 7;
        const ptrdiff_t goff = ((ptrdiff_t)(t / 3) - 1) * lv.P2W + (t % 3) - 1;
        const unsigned short* bt = bgh + (size_t)kb * PP32 + goff * 32;
        gload16(bt,       lbW + slot * 8192);
        gload16(bt + 512, lbW + slot * 8192 + 512);
    };

    // one K-half (32 ci): 2 phases of 16 MFMA (i 0..3 / 4..7), staging s+3
    auto half_body = [&](int h, bool dostage) {
        const int off = (h & 3) * 8192;
        v8s af[4], bfr[4];
#pragma unroll
        for (int j = 0; j < 4; ++j) bfr[j] = *(const v8s*)&sB[off + brd[j]];
#pragma unroll
        for (int i = 0; i < 4; ++i) af[i] = *(const v8s*)&sA[off + ard[i]];
        if (dostage) stageA2(h + 3);
        __builtin_amdgcn_sched_barrier(0);
        LGKM0;
        __builtin_amdgcn_s_setprio(1);
#pragma unroll
        for (int i = 0; i < 4; ++i)
#pragma unroll
            for (int j = 0; j < 4; ++j)
                acc[i][j] = __builtin_amdgcn_mfma_f32_16x16x32_bf16(
                    af[i], bfr[j], acc[i][j], 0, 0, 0);
        __builtin_amdgcn_s_setprio(0);
        __builtin_amdgcn_s_barrier();                 // phase split
#pragma unroll
        for (int i = 0; i < 4; ++i) af[i] = *(const v8s*)&sA[off + ard[4 + i]];
        if (dostage) stageB2(h + 3);
        __builtin_amdgcn_sched_barrier(0);
        LGKM0;
        __builtin_amdgcn_s_setprio(1);
#pragma unroll
        for (int i = 0; i < 4; ++i)
#pragma unroll
            for (int j = 0; j < 4; ++j)
                acc[4 + i][j] = __builtin_amdgcn_mfma_f32_16x16x32_bf16(
                    af[i], bfr[j], acc[4 + i][j], 0, 0, 0);
        __builtin_amdgcn_s_setprio(0);
    };

    // prologue: halves 0,1,2 in flight (12 gloads/wave-sym, 4 per half)
    stageA2(0); stageB2(0);
    stageA2(1); stageB2(1);
    stageA2(2); stageB2(2);
#pragma unroll 1
    for (int h = 0; h < 69; ++h) {
        vwait<8>();                          // own 4 of half h retired
        __builtin_amdgcn_s_barrier();        // all waves: half h complete
        __builtin_amdgcn_sched_barrier(0);
        half_body(h, true);
    }
    vwait<8>(); __builtin_amdgcn_s_barrier(); __builtin_amdgcn_sched_barrier(0);
    half_body(69, false);
    vwait<4>(); __builtin_amdgcn_s_barrier(); __builtin_amdgcn_sched_barrier(0);
    half_body(70, false);
    vwait<0>(); __builtin_amdgcn_s_barrier(); __builtin_amdgcn_sched_barrier(0);
    half_body(71, false);

    if (!HEAD) {
        unsigned short* yb = yout + (size_t)br * XELs + (size_t)lv.xo +
                             (size_t)n * lv.PP * 256;
        const int slot = br * 3 + layer;
#pragma unroll
        for (int i = 0; i < 8; ++i) {
            const int cobase = m * 128 + i * 16 + q * 4;
            const float4 b4 = *(const float4*)(bias + cobase);
            const size_t kbo = (size_t)(cobase >> 5) * PP32;
            const int cc = cobase & 31;
            float s = 0.f, ss = 0.f;
#pragma unroll
            for (int j = 0; j < 4; ++j) {
                const int pp = pp0 + nn * 64 + j * 16 + col;
                const unsigned h2 = (unsigned)pp / (unsigned)lv.P2W;
                const unsigned w2 = (unsigned)pp - h2 * lv.P2W;
                const bool in = (h2 >= 1u) & (h2 <= (unsigned)lv.H) &
                                (w2 >= 1u) & (w2 <= (unsigned)lv.W);
                float v0 = acc[i][j][0] + b4.x;
                float v1 = acc[i][j][1] + b4.y;
                float v2 = acc[i][j][2] + b4.z;
                float v3 = acc[i][j][3] + b4.w;
                if (in) {
                    ushort4 pk;
                    pk.x = f2bf(v0); pk.y = f2bf(v1);
                    pk.z = f2bf(v2); pk.w = f2bf(v3);
                    *(ushort4*)(yb + kbo + (size_t)pp * 32 + cc) = pk;
                    s  += v0 + v1 + v2 + v3;
                    ss += v0 * v0 + v1 * v1 + v2 * v2 + v3 * v3;
                }
            }
#pragma unroll
            for (int o = 32; o > 0; o >>= 1) {
                s  += __shfl_down(s, o, 64);
                ss += __shfl_down(ss, o, 64);
            }
            if (lane == 0) {
                const int g = cobase >> 4;
                const int si = (((slot * 5 + L) * 32) + n * 16 + g) * 2;
                atomicAdd(&stats[si + 0], s);
                atomicAdd(&stats[si + 1], ss);
            }
        }
    } else {
#pragma unroll
        for (int i = 0; i < 8; ++i) {
            const int cobase = m * 128 + i * 16 + q * 4;
            float bv[4];
#pragma unroll
            for (int k = 0; k < 4; ++k)
                bv[k] = (cobase + k < CO) ? bias[cobase + k] : 0.f;
#pragma unroll
            for (int j = 0; j < 4; ++j) {
                const int pp = pp0 + nn * 64 + j * 16 + col;
                const unsigned h2 = (unsigned)pp / (unsigned)lv.P2W;
                const unsigned w2 = (unsigned)pp - h2 * lv.P2W;
                const bool in = (h2 >= 1u) & (h2 <= (unsigned)lv.H) &
                                (w2 >= 1u) & (w2 <= (unsigned)lv.W);
                if (in) {
                    const int p = (h2 - 1) * lv.W + (w2 - 1);
                    float* ob = out + ((size_t)n * TPOINTS + lv.loff + p) * 85 + co_out;
#pragma unroll
                    for (int k = 0; k < 4; ++k) {
                        const int co = cobase + k;
                        if (co < CO) {
                            float v = acc[i][j][k] + bv[k];
                            if (co < relu_cnt) v = fmaxf(v, 0.f);
                            ob[co] = v;
                        }
                    }
                }
            }
        }
    }
}

// ---------------------------------------------------------------------------
// Small reg-head (bbox+ctr, CO=5) — ci-blocked addressing (proven r3).
// ---------------------------------------------------------------------------
__global__ __launch_bounds__(256) void head5_k(
    const unsigned short* __restrict__ xin,
    const unsigned short* __restrict__ wt,
    const float* __restrict__ bias, float* __restrict__ out, Tab tb)
{
    __shared__ unsigned short sA[16 * 32];
    __shared__ unsigned short sB[256 * 32];
    const int tid = threadIdx.x, lane = tid & 63, wave = tid >> 6;
    const int bx = blockIdx.x, n = blockIdx.z;
    int L = 0;
    while (L < 4 && bx >= tb.lv[L + 1].t_h5) ++L;
    const Lv lv = tb.lv[L];
    const int pp0 = (bx - lv.t_h5) * 256;
    const size_t PP32 = (size_t)lv.PP * 32;

    v4f acc[4];
#pragma unroll
    for (int j = 0; j < 4; ++j) acc[j] = (v4f)0.f;

    const unsigned short* xb = xin + (size_t)lv.xo + (size_t)n * lv.PP * 256;
    const unsigned short* brow = xb + (size_t)(pp0 + tid) * 32;
    const int bs = (tid >> 1) & 3;
    int bw[4];
#pragma unroll
    for (int c = 0; c < 4; ++c) bw[c] = tid * 32 + ((c ^ bs) << 3);

    const int col = lane & 15, q = lane >> 4;
    const int qs = (q ^ ((col >> 1) & 3)) << 3;
    const int ard = col * 32 + qs;
    const int wb = wave * 64;
    int brd[4];
#pragma unroll
    for (int j = 0; j < 4; ++j) brd[j] = (wb + j * 16 + col) * 32 + qs;

    for (int step = 0; step < 72; ++step) {
        const int t = step >> 3, kb = step & 7;
        const ptrdiff_t off = ((ptrdiff_t)(t / 3) - 1) * lv.P2W + (t % 3) - 1;
        const unsigned short* bt = brow + (size_t)kb * PP32 + off * 32;
        uint4 bv[4];
#pragma unroll
        for (int c = 0; c < 4; ++c) bv[c] = *(const uint4*)(bt + c * 8);
        uint4 av[4];
        if (tid < 16) {
            const unsigned short* at = wt + (size_t)((step) * 16 + tid) * 32;
#pragma unroll
            for (int c = 0; c < 4; ++c) av[c] = *(const uint4*)(at + c * 8);
        }
        __syncthreads();
#pragma unroll
        for (int c = 0; c < 4; ++c) *(uint4*)&sB[bw[c]] = bv[c];
        if (tid < 16) {
#pragma unroll
            for (int c = 0; c < 4; ++c) *(uint4*)&sA[bw[c]] = av[c];
        }
        __syncthreads();
        v8s af = *(const v8s*)&sA[ard];
        v8s bfr[4];
#pragma unroll
        for (int j = 0; j < 4; ++j) bfr[j] = *(const v8s*)&sB[brd[j]];
#pragma unroll
        for (int j = 0; j < 4; ++j)
            acc[j] = __builtin_amdgcn_mfma_f32_16x16x32_bf16(
                af, bfr[j], acc[j], 0, 0, 0);
    }

    float bv4[4];
#pragma unroll
    for (int k = 0; k < 4; ++k) {
        const int co = q * 4 + k;
        bv4[k] = (co < 5) ? bias[co] : 0.f;
    }
#pragma unroll
    for (int j = 0; j < 4; ++j) {
        const int pp = pp0 + wb + j * 16 + col;
        const unsigned h2 = (unsigned)pp / (unsigned)lv.P2W;
        const unsigned w2 = (unsigned)pp - h2 * lv.P2W;
        const bool in = (h2 >= 1u) & (h2 <= (unsigned)lv.H) &
                        (w2 >= 1u) & (w2 <= (unsigned)lv.W);
        if (in) {
            const int p = (h2 - 1) * lv.W + (w2 - 1);
            float* ob = out + ((size_t)n * TPOINTS + lv.loff + p) * 85 + 80;
#pragma unroll
            for (int k = 0; k < 4; ++k) {
                const int co = q * 4 + k;
                if (co < 5) {
                    float v = acc[j][k] + bv4[k];
                    if (co < 4) v = fmaxf(v, 0.f);
                    ob[co] = v;
                }
            }
        }
    }
}

// ---------------------------------------------------------------------------
// GN + affine + ReLU, in-place, fused across levels AND branches (z=br*2+n).
// ---------------------------------------------------------------------------
__global__ __launch_bounds__(256) void gn_k(
    unsigned short* __restrict__ x, const float* __restrict__ stats, int layer,
    const float* __restrict__ g_c, const float* __restrict__ be_c,
    const float* __restrict__ g_r, const float* __restrict__ be_r, Tab tb)
{
    const int tid = threadIdx.x, bx = blockIdx.x, z = blockIdx.z;
    const int n = z & 1, br = z >> 1;
    const size_t XELs = 9200640;
    int L = 0;
    while (L < 4 && bx >= tb.lv[L + 1].t_gn) ++L;
    const Lv lv = tb.lv[L];
    const int pos = (bx - lv.t_gn) * 32 + (tid >> 3);
    if (pos >= lv.HW) return;
    const int slot = br * 3 + layer;
    const float* gamma = (br ? g_r : g_c) + layer * 256;
    const float* beta  = (br ? be_r : be_c) + layer * 256;
    const int c0 = (tid & 7) * 32;
    const int h = pos >> lv.lwW, w = pos & (lv.W - 1);
    const int pp = (h + 1) * lv.P2W + (w + 1);
    unsigned short* p = x + (size_t)br * XELs + (size_t)lv.xo +
                        (size_t)n * lv.PP * 256 +
                        (size_t)(tid & 7) * lv.PP * 32 + (size_t)pp * 32;
    const float inv = 1.0f / (16.0f * (float)lv.HW);
    const int sb = ((slot * 5 + L) * 32 + n * 16) * 2;

    float scv[32], shv[32];
#pragma unroll
    for (int gg = 0; gg < 2; ++gg) {
        const int g = (c0 >> 4) + gg;
        const float mm = stats[sb + g * 2 + 0] * inv;
        const float v = stats[sb + g * 2 + 1] * inv - mm * mm;
        const float rs = rsqrtf(v + GN_EPS);
#pragma unroll
        for (int k = 0; k < 16; ++k) {
            const int c = g * 16 + k;
            const float sc = rs * gamma[c];
            scv[gg * 16 + k] = sc;
            shv[gg * 16 + k] = beta[c] - mm * sc;
        }
    }
#pragma unroll
    for (int u = 0; u < 4; ++u) {
        uint4 a = *(const uint4*)(p + u * 8);
        unsigned wds[4] = {a.x, a.y, a.z, a.w};
#pragma unroll
        for (int k = 0; k < 4; ++k) {
            const int e = u * 8 + k * 2;
            float lo = bf2f((unsigned short)(wds[k] & 0xffffu));
            float hi = bf2f((unsigned short)(wds[k] >> 16));
            lo = fmaxf(lo * scv[e]     + shv[e],     0.f);
            hi = fmaxf(hi * scv[e + 1] + shv[e + 1], 0.f);
            wds[k] = (unsigned)f2bf(lo) | ((unsigned)f2bf(hi) << 16);
        }
        uint4 o; o.x = wds[0]; o.y = wds[1]; o.z = wds[2]; o.w = wds[3];
        *(uint4*)(p + u * 8) = o;
    }
}

// ---------------------------------------------------------------------------
// fp32 NCHW feats -> bf16 ci-blocked padded interior.
// ---------------------------------------------------------------------------
__global__ __launch_bounds__(256) void prepx_k(
    const float* f0, const float* f1, const float* f2, const float* f3,
    const float* f4, unsigned short* __restrict__ xo, Tab tb)
{
    const float* fs[5] = {f0, f1, f2, f3, f4};
    const int tid = threadIdx.x, bx = blockIdx.x, n = blockIdx.z;
    int L = 0;
    while (L < 4 && bx >= tb.lv[L + 1].t_prep) ++L;
    const Lv lv = tb.lv[L];
    const int pos = (bx - lv.t_prep) * 64 + (tid & 63);
    const int wave = tid >> 6;
    if (pos >= lv.HW) return;
    const int h = pos >> lv.lwW, w = pos & (lv.W - 1);
    const int pp = (h + 1) * lv.P2W + (w + 1);
    const float* src = fs[L] + (size_t)n * 256 * lv.HW + pos;
    unsigned short* dst = xo + (size_t)lv.xo + (size_t)n * lv.PP * 256;
#pragma unroll
    for (int k = 0; k < 16; ++k) {
        const int c = wave * 64 + k * 4;
        ushort4 pk;
        pk.x = f2bf(src[(size_t)(c + 0) * lv.HW]);
        pk.y = f2bf(src[(size_t)(c + 1) * lv.HW]);
        pk.z = f2bf(src[(size_t)(c + 2) * lv.HW]);
        pk.w = f2bf(src[(size_t)(c + 3) * lv.HW]);
        *(ushort4*)(dst + (size_t)(c >> 5) * lv.PP * 32 +
                    (size_t)pp * 32 + (c & 31)) = pk;
    }
}

// ---------------------------------------------------------------------------
// tower weights: [br][layer][tap][kb][co 256][32ci] (per-step tile contiguous)
__global__ __launch_bounds__(256) void prepwt_k(
    const float* __restrict__ cw, const float* __restrict__ rw,
    unsigned short* __restrict__ dst)
{
    const int idx = blockIdx.x * 256 + threadIdx.x;   // 54*65536
    const int ci = idx & 255, co = (idx >> 8) & 255, r = idx >> 16;
    const int tap = r % 9, layer = (r / 9) % 3, br = r / 27;
    const float* s = br ? rw : cw;
    dst[(size_t)r * 65536 + (size_t)(((ci >> 5) * 256 + co) * 32) + (ci & 31)] =
        f2bf(s[(((size_t)layer * 256 + co) * 256 + ci) * 9 + tap]);
}

// head weights: [tap][kb][co rows][32ci]
__global__ __launch_bounds__(256) void prepwh_k(
    const float* __restrict__ src, unsigned short* __restrict__ dst,
    int CO, int rows, int roff)
{
    const int idx = blockIdx.x * 256 + threadIdx.x;
    if (idx >= CO * 2304) return;
    const int ci = idx & 255, rr = idx >> 8;
    const int tap = rr % 9, co = rr / 9;
    dst[((size_t)(tap * 8 + (ci >> 5)) * rows + roff + co) * 32 + (ci & 31)] =
        f2bf(src[((size_t)co * 256 + ci) * 9 + tap]);
}

// ---------------------------------------------------------------------------
extern "C" void kernel_launch(void* const* d_in, const int* in_sizes, int n_in,
                              void* d_out, int out_size, void* d_ws, size_t ws_size,
                              hipStream_t stream) {
    const float* f0 = (const float*)d_in[0];
    const float* f1 = (const float*)d_in[1];
    const float* f2 = (const float*)d_in[2];
    const float* f3 = (const float*)d_in[3];
    const float* f4 = (const float*)d_in[4];
    const float* cls_w  = (const float*)d_in[5];
    const float* cls_b  = (const float*)d_in[6];
    const float* cls_g  = (const float*)d_in[7];
    const float* cls_be = (const float*)d_in[8];
    const float* log_w  = (const float*)d_in[9];
    const float* log_b  = (const float*)d_in[10];
    const float* reg_w  = (const float*)d_in[11];
    const float* reg_b  = (const float*)d_in[12];
    const float* reg_g  = (const float*)d_in[13];
    const float* reg_be = (const float*)d_in[14];
    const float* bbox_w = (const float*)d_in[15];
    const float* bbox_b = (const float*)d_in[16];
    const float* ctr_w  = (const float*)d_in[17];
    const float* ctr_b  = (const float*)d_in[18];
    float* out = (float*)d_out;

    Tab tb;
    //            t_conv t_gn t_prep t_h5 xo       P2W  PP     HW     W    H   lwW loff
    tb.lv[0] = {   0,    0,    0,    0,   0,       130, 13260, 12800, 128, 100, 7, 0     };
    tb.lv[1] = { 104,  400,  200,  52,  6789120,    66,  3432,  3200,  64,  50, 6, 12800 };
    tb.lv[2] = { 131,  500,  250,  66,  8546304,    34,   918,   800,  32,  25, 5, 16000 };
    tb.lv[3] = { 139,  525,  263,  70,  9016320,    18,   270,   208,  16,  13, 4, 16800 };
    tb.lv[4] = { 142,  532,  267,  72,  9154560,    10,    90,    56,   8,   7, 3, 17008 };
    const int NT_GN = 534, NT_PREP = 268, NT_H5 = 73;
    const size_t XEL = 9200640;

    char* base = (char*)d_ws;
    size_t o = 0;
    auto take = [&](size_t bytes) {
        char* p = base + o; o += (bytes + 255) & ~(size_t)255; return p;
    };
    take(131072);                                        // guard 128KB
    unsigned short* PX = (unsigned short*)take(XEL * 2);          // shared input
    take(131072);
    unsigned short* B1 = (unsigned short*)take(XEL * 2 * 2);      // [br]
    take(131072);
    unsigned short* B2 = (unsigned short*)take(XEL * 2 * 2);      // [br]
    take(131072);
    unsigned short* WT  = (unsigned short*)take((size_t)54 * 65536 * 2);
    unsigned short* WHC = (unsigned short*)take((size_t)72 * 256 * 32 * 2); // 256-row padded
    unsigned short* WHR = (unsigned short*)take((size_t)9 * 16 * 256 * 2);
    float* ST  = (float*)take(1920 * 4);
    float* RB5 = (float*)take(32);

    hipMemsetAsync(PX, 0, XEL * 2, stream);
    hipMemsetAsync(B1, 0, XEL * 4, stream);
    hipMemsetAsync(B2, 0, XEL * 4, stream);
    hipMemsetAsync(ST, 0, 1920 * 4, stream);
    hipMemsetAsync(WHC, 0, (size_t)72 * 256 * 32 * 2, stream);
    hipMemsetAsync(WHR, 0, (size_t)9 * 16 * 256 * 2, stream);
    hipMemcpyAsync(RB5,     bbox_b, 4 * 4, hipMemcpyDeviceToDevice, stream);
    hipMemcpyAsync(RB5 + 4, ctr_b,  1 * 4, hipMemcpyDeviceToDevice, stream);

    prepwt_k<<<dim3(13824), dim3(256), 0, stream>>>(cls_w, reg_w, WT);
    prepwh_k<<<dim3(720), dim3(256), 0, stream>>>(log_w,  WHC, 80, 256, 0);
    prepwh_k<<<dim3(36),  dim3(256), 0, stream>>>(bbox_w, WHR, 4, 16, 0);
    prepwh_k<<<dim3(9),   dim3(256), 0, stream>>>(ctr_w,  WHR, 1, 16, 4);

    prepx_k<<<dim3(NT_PREP, 1, 2), dim3(256), 0, stream>>>(f0, f1, f2, f3, f4, PX, tb);

    // chain: conv0 PX->B1[br], gn0 B1; conv1 B1->B2, gn1 B2; conv2 B2->B1,
    // gn2 B1; cls-head B1[0]; reg-head5 B1[1].
    const size_t WBRS = (size_t)27 * 65536;
    unsigned short* cin[3]  = {PX, B1, B2};
    size_t          cbrs[3] = {0, XEL, XEL};
    unsigned short* cout_[3] = {B1, B2, B1};
    for (int i = 0; i < 3; ++i) {
        conv_k<0><<<dim3(NT_H5, 1, 4), dim3(512), 0, stream>>>(
            cin[i], cbrs[i], WT + (size_t)i * 9 * 65536, WBRS, 256,
            cls_b + i * 256, reg_b + i * 256,
            cout_[i], ST, i, nullptr, 0, 0, 0, tb);
        gn_k<<<dim3(NT_GN, 1, 4), dim3(256), 0, stream>>>(
            cout_[i], ST, i, cls_g, cls_be, reg_g, reg_be, tb);
    }
    conv_k<1><<<dim3(NT_H5, 1, 2), dim3(512), 0, stream>>>(
        B1, 0, WHC, 0, 256, log_b, log_b,
        nullptr, nullptr, 0, out, NCLS, 0, 0, tb);
    head5_k<<<dim3(NT_H5, 1, 2), dim3(256), 0, stream>>>(
        B1 + XEL, WHR, RB5, out, tb);
}

// Round 7
// 1034.064 us; speedup vs baseline: 1.1745x; 1.1080x over previous
//
#include <hip/hip_runtime.h>

#define NCLS 80
#define TPOINTS 17064
#define GN_EPS 1e-5f

typedef float v4f __attribute__((ext_vector_type(4)));
typedef short v8s __attribute__((ext_vector_type(8)));

__device__ __forceinline__ unsigned short f2bf(float f) {
    unsigned u = __float_as_uint(f);
    unsigned r = (u + 0x7FFFu + ((u >> 16) & 1u)) >> 16;
    return (unsigned short)r;
}
__device__ __forceinline__ float bf2f(unsigned short h) {
    return __uint_as_float(((unsigned)h) << 16);
}
__device__ __forceinline__ void gload16(const unsigned short* g, unsigned short* l) {
    __builtin_amdgcn_global_load_lds(
        (const __attribute__((address_space(1))) unsigned int*)g,
        (__attribute__((address_space(3))) unsigned int*)l, 16, 0, 0);
}
template<int N> __device__ __forceinline__ void vwait() {
    asm volatile("s_waitcnt vmcnt(%0)" :: "n"(N) : "memory");
    __builtin_amdgcn_sched_barrier(0);
}
#define LGKM0 do { asm volatile("s_waitcnt lgkmcnt(0)" ::: "memory"); \
                   __builtin_amdgcn_sched_barrier(0); } while (0)

struct Lv { int t_conv, t_gn, t_prep, t_h5, xo, P2W, PP, HW, W, H, lwW, loff; };
struct Tab { Lv lv[5]; };

// ---------------------------------------------------------------------------
// Implicit-GEMM conv, 8-wave deep-pipeline structure at 2 BLOCKS/CU.
// r5: 256^2 tile @128KB LDS = 1 block/CU; 292 blocks -> two dispatch rounds
// (2nd 14% full); occupancy 15.0% matched packing model; in-block MfmaUtil
// ~2x round 0. r6: re-tiled to 128-pos tiles but derived tile counts from
// HW instead of padded PP -> missing output tiles -> absmax fail. r7 =
// r6 with the CORRECT ceil(PP/128) table {104,27,8,3,1} (cum 0,104,131,
// 139,142; NT=143 — same as r0-r4, which used identical 128-pos geometry).
// Structure: tile 256co x 128pos, 8 waves (4co x 2pos, 64x64, acc[4][4]);
// 3-deep pipeline; LDS 3*(16KB A + 8KB B)=72KB -> 2 blocks/CU
// (launch_bounds(512,4) caps VGPR 128). Grid 143 tiles x z4 = 572 blocks
// @512 resident -> ~11% tail (was 83%). Per half: 3 gloads/wave (2A+1B,
// uniform), staged 2 halves ahead; vwait(6) -> barrier (half ready) ->
// 8 ds_read_b128 -> lgkmcnt(0) -> barrier (slot free) -> stage h+3 ->
// setprio + 16 MFMA. Tail vwait 3/0. XOR chunk-swizzle deposit/read as
// r0-r5 (0 bank conflicts measured).
// TOWER (HEAD=0): bf16 ci-blocked out + fused GN stats. HEAD=1: fp32 out.
// ---------------------------------------------------------------------------
template<int HEAD>
__global__ __launch_bounds__(512, 4) void conv_k(
    const unsigned short* __restrict__ xin, size_t xin_brs,
    const unsigned short* __restrict__ wt, size_t wt_brs, int wrows,
    const float* __restrict__ bias_c, const float* __restrict__ bias_r,
    unsigned short* __restrict__ yout, float* __restrict__ stats, int layer,
    float* __restrict__ out, int CO, int co_out, int relu_cnt,
    Tab tb)
{
    __shared__ __align__(16) unsigned short sA[3 * 256 * 32];   // 48KB
    __shared__ __align__(16) unsigned short sB[3 * 128 * 32];   // 24KB
    const int tid = threadIdx.x, lane = tid & 63, wave = tid >> 6;
    const int bx = blockIdx.x, z = blockIdx.z;
    const int n = z & 1, br = z >> 1;
    int L = 0;
    while (L < 4 && bx >= tb.lv[L + 1].t_conv) ++L;
    const Lv lv = tb.lv[L];
    const int pp0 = (bx - lv.t_conv) * 128;
    const size_t XELs = 9200640;
    const size_t PP32 = (size_t)lv.PP * 32;

    v4f acc[4][4];
#pragma unroll
    for (int i = 0; i < 4; ++i)
#pragma unroll
        for (int j = 0; j < 4; ++j) acc[i][j] = (v4f)0.f;

    const unsigned short* wtb = wt + (size_t)br * wt_brs;
    const float* bias = br ? bias_r : bias_c;
    const unsigned short* xb = xin + (size_t)br * xin_brs +
                               (size_t)lv.xo + (size_t)n * lv.PP * 256;

    // staging: A: wave w rows [w*32, +32) of 256; B: wave w rows [w*16, +16)
    // of 128. lane l -> row += l>>2, source chunk (l&3)^((l>>3)&3) (LDS holds
    // row-XOR-swizzled chunks; == chunk ^ ((row>>1)&3) for 16-row groups).
    const int lr = lane >> 2;
    const int lc = ((lane & 3) ^ ((lane >> 3) & 3)) * 8;
    const unsigned short* ag = wtb + (size_t)(wave * 32 + lr) * 32 + lc;
    const unsigned short* bgh = xb + (ptrdiff_t)(pp0 + wave * 16 + lr) * 32 + lc;
    unsigned short* laW = &sA[wave * 32 * 32];
    unsigned short* lbW = &sB[wave * 16 * 32];
    const size_t wstride2 = (size_t)wrows * 32;   // elems per K-half A tile

    const int col = lane & 15, q = lane >> 4;
    const int wr = wave & 3, wc = wave >> 2;      // 4 co-blocks x 2 pos-blocks
    const int qs = (q ^ ((col >> 1) & 3)) << 3;
    int ard[4], brd[4];
#pragma unroll
    for (int i = 0; i < 4; ++i) ard[i] = (wr * 64 + i * 16 + col) * 32 + qs;
#pragma unroll
    for (int j = 0; j < 4; ++j) brd[j] = (wc * 64 + j * 16 + col) * 32 + qs;

    auto stageHalf = [&](int s) {
        const int slot = s % 3;
        const unsigned short* at = ag + (size_t)s * wstride2;
        gload16(at,       laW + slot * 8192);
        gload16(at + 512, laW + slot * 8192 + 512);
        const int t = s >> 3, kb = s & 7;
        const ptrdiff_t goff = ((ptrdiff_t)(t / 3) - 1) * lv.P2W + (t % 3) - 1;
        gload16(bgh + (size_t)kb * PP32 + goff * 32, lbW + slot * 4096);
    };

    auto half_body = [&](int h, bool dostage) {
        const int sa = (h % 3) * 8192, sb_ = (h % 3) * 4096;
        v8s af[4], bfr[4];
#pragma unroll
        for (int i = 0; i < 4; ++i) af[i]  = *(const v8s*)&sA[sa + ard[i]];
#pragma unroll
        for (int j = 0; j < 4; ++j) bfr[j] = *(const v8s*)&sB[sb_ + brd[j]];
        LGKM0;                                   // frags in regs
        __builtin_amdgcn_s_barrier();            // all waves done reading slot
        if (dostage) stageHalf(h + 3);           // safe: slot (h+3)%3 == h%3
        __builtin_amdgcn_sched_barrier(0);
        __builtin_amdgcn_s_setprio(1);
#pragma unroll
        for (int i = 0; i < 4; ++i)
#pragma unroll
            for (int j = 0; j < 4; ++j)
                acc[i][j] = __builtin_amdgcn_mfma_f32_16x16x32_bf16(
                    af[i], bfr[j], acc[i][j], 0, 0, 0);
        __builtin_amdgcn_s_setprio(0);
    };

    // prologue: halves 0,1,2 in flight (9 gloads/wave, 3 per half)
    stageHalf(0); stageHalf(1); stageHalf(2);
#pragma unroll 1
    for (int h = 0; h < 70; ++h) {
        vwait<6>();                          // own 3 of half h retired
        __builtin_amdgcn_s_barrier();        // all waves: half h complete
        half_body(h, h < 69);
    }
    vwait<3>(); __builtin_amdgcn_s_barrier(); half_body(70, false);
    vwait<0>(); __builtin_amdgcn_s_barrier(); half_body(71, false);

    if (!HEAD) {
        unsigned short* yb = yout + (size_t)br * XELs + (size_t)lv.xo +
                             (size_t)n * lv.PP * 256;
        const int slot = br * 3 + layer;
#pragma unroll
        for (int i = 0; i < 4; ++i) {
            const int cobase = wr * 64 + i * 16 + q * 4;
            const float4 b4 = *(const float4*)(bias + cobase);
            const size_t kbo = (size_t)(cobase >> 5) * PP32;
            const int cc = cobase & 31;
            float s = 0.f, ss = 0.f;
#pragma unroll
            for (int j = 0; j < 4; ++j) {
                const int pp = pp0 + wc * 64 + j * 16 + col;
                const unsigned h2 = (unsigned)pp / (unsigned)lv.P2W;
                const unsigned w2 = (unsigned)pp - h2 * lv.P2W;
                const bool in = (h2 >= 1u) & (h2 <= (unsigned)lv.H) &
                                (w2 >= 1u) & (w2 <= (unsigned)lv.W);
                float v0 = acc[i][j][0] + b4.x;
                float v1 = acc[i][j][1] + b4.y;
                float v2 = acc[i][j][2] + b4.z;
                float v3 = acc[i][j][3] + b4.w;
                if (in) {
                    ushort4 pk;
                    pk.x = f2bf(v0); pk.y = f2bf(v1);
                    pk.z = f2bf(v2); pk.w = f2bf(v3);
                    *(ushort4*)(yb + kbo + (size_t)pp * 32 + cc) = pk;
                    s  += v0 + v1 + v2 + v3;
                    ss += v0 * v0 + v1 * v1 + v2 * v2 + v3 * v3;
                }
            }
#pragma unroll
            for (int o = 32; o > 0; o >>= 1) {
                s  += __shfl_down(s, o, 64);
                ss += __shfl_down(ss, o, 64);
            }
            if (lane == 0) {
                const int g = cobase >> 4;
                const int si = (((slot * 5 + L) * 32) + n * 16 + g) * 2;
                atomicAdd(&stats[si + 0], s);
                atomicAdd(&stats[si + 1], ss);
            }
        }
    } else {
#pragma unroll
        for (int i = 0; i < 4; ++i) {
            const int cobase = wr * 64 + i * 16 + q * 4;
            float bv[4];
#pragma unroll
            for (int k = 0; k < 4; ++k)
                bv[k] = (cobase + k < CO) ? bias[cobase + k] : 0.f;
#pragma unroll
            for (int j = 0; j < 4; ++j) {
                const int pp = pp0 + wc * 64 + j * 16 + col;
                const unsigned h2 = (unsigned)pp / (unsigned)lv.P2W;
                const unsigned w2 = (unsigned)pp - h2 * lv.P2W;
                const bool in = (h2 >= 1u) & (h2 <= (unsigned)lv.H) &
                                (w2 >= 1u) & (w2 <= (unsigned)lv.W);
                if (in) {
                    const int p = (h2 - 1) * lv.W + (w2 - 1);
                    float* ob = out + ((size_t)n * TPOINTS + lv.loff + p) * 85 + co_out;
#pragma unroll
                    for (int k = 0; k < 4; ++k) {
                        const int co = cobase + k;
                        if (co < CO) {
                            float v = acc[i][j][k] + bv[k];
                            if (co < relu_cnt) v = fmaxf(v, 0.f);
                            ob[co] = v;
                        }
                    }
                }
            }
        }
    }
}

// ---------------------------------------------------------------------------
// Small reg-head (bbox+ctr, CO=5) — ci-blocked addressing (proven r3).
// ---------------------------------------------------------------------------
__global__ __launch_bounds__(256) void head5_k(
    const unsigned short* __restrict__ xin,
    const unsigned short* __restrict__ wt,
    const float* __restrict__ bias, float* __restrict__ out, Tab tb)
{
    __shared__ unsigned short sA[16 * 32];
    __shared__ unsigned short sB[256 * 32];
    const int tid = threadIdx.x, lane = tid & 63, wave = tid >> 6;
    const int bx = blockIdx.x, n = blockIdx.z;
    int L = 0;
    while (L < 4 && bx >= tb.lv[L + 1].t_h5) ++L;
    const Lv lv = tb.lv[L];
    const int pp0 = (bx - lv.t_h5) * 256;
    const size_t PP32 = (size_t)lv.PP * 32;

    v4f acc[4];
#pragma unroll
    for (int j = 0; j < 4; ++j) acc[j] = (v4f)0.f;

    const unsigned short* xb = xin + (size_t)lv.xo + (size_t)n * lv.PP * 256;
    const unsigned short* brow = xb + (size_t)(pp0 + tid) * 32;
    const int bs = (tid >> 1) & 3;
    int bw[4];
#pragma unroll
    for (int c = 0; c < 4; ++c) bw[c] = tid * 32 + ((c ^ bs) << 3);

    const int col = lane & 15, q = lane >> 4;
    const int qs = (q ^ ((col >> 1) & 3)) << 3;
    const int ard = col * 32 + qs;
    const int wb = wave * 64;
    int brd[4];
#pragma unroll
    for (int j = 0; j < 4; ++j) brd[j] = (wb + j * 16 + col) * 32 + qs;

    for (int step = 0; step < 72; ++step) {
        const int t = step >> 3, kb = step & 7;
        const ptrdiff_t off = ((ptrdiff_t)(t / 3) - 1) * lv.P2W + (t % 3) - 1;
        const unsigned short* bt = brow + (size_t)kb * PP32 + off * 32;
        uint4 bv[4];
#pragma unroll
        for (int c = 0; c < 4; ++c) bv[c] = *(const uint4*)(bt + c * 8);
        uint4 av[4];
        if (tid < 16) {
            const unsigned short* at = wt + (size_t)((step) * 16 + tid) * 32;
#pragma unroll
            for (int c = 0; c < 4; ++c) av[c] = *(const uint4*)(at + c * 8);
        }
        __syncthreads();
#pragma unroll
        for (int c = 0; c < 4; ++c) *(uint4*)&sB[bw[c]] = bv[c];
        if (tid < 16) {
#pragma unroll
            for (int c = 0; c < 4; ++c) *(uint4*)&sA[bw[c]] = av[c];
        }
        __syncthreads();
        v8s af = *(const v8s*)&sA[ard];
        v8s bfr[4];
#pragma unroll
        for (int j = 0; j < 4; ++j) bfr[j] = *(const v8s*)&sB[brd[j]];
#pragma unroll
        for (int j = 0; j < 4; ++j)
            acc[j] = __builtin_amdgcn_mfma_f32_16x16x32_bf16(
                af, bfr[j], acc[j], 0, 0, 0);
    }

    float bv4[4];
#pragma unroll
    for (int k = 0; k < 4; ++k) {
        const int co = q * 4 + k;
        bv4[k] = (co < 5) ? bias[co] : 0.f;
    }
#pragma unroll
    for (int j = 0; j < 4; ++j) {
        const int pp = pp0 + wb + j * 16 + col;
        const unsigned h2 = (unsigned)pp / (unsigned)lv.P2W;
        const unsigned w2 = (unsigned)pp - h2 * lv.P2W;
        const bool in = (h2 >= 1u) & (h2 <= (unsigned)lv.H) &
                        (w2 >= 1u) & (w2 <= (unsigned)lv.W);
        if (in) {
            const int p = (h2 - 1) * lv.W + (w2 - 1);
            float* ob = out + ((size_t)n * TPOINTS + lv.loff + p) * 85 + 80;
#pragma unroll
            for (int k = 0; k < 4; ++k) {
                const int co = q * 4 + k;
                if (co < 5) {
                    float v = acc[j][k] + bv4[k];
                    if (co < 4) v = fmaxf(v, 0.f);
                    ob[co] = v;
                }
            }
        }
    }
}

// ---------------------------------------------------------------------------
// GN + affine + ReLU, in-place, fused across levels AND branches (z=br*2+n).
// ---------------------------------------------------------------------------
__global__ __launch_bounds__(256) void gn_k(
    unsigned short* __restrict__ x, const float* __restrict__ stats, int layer,
    const float* __restrict__ g_c, const float* __restrict__ be_c,
    const float* __restrict__ g_r, const float* __restrict__ be_r, Tab tb)
{
    const int tid = threadIdx.x, bx = blockIdx.x, z = blockIdx.z;
    const int n = z & 1, br = z >> 1;
    const size_t XELs = 9200640;
    int L = 0;
    while (L < 4 && bx >= tb.lv[L + 1].t_gn) ++L;
    const Lv lv = tb.lv[L];
    const int pos = (bx - lv.t_gn) * 32 + (tid >> 3);
    if (pos >= lv.HW) return;
    const int slot = br * 3 + layer;
    const float* gamma = (br ? g_r : g_c) + layer * 256;
    const float* beta  = (br ? be_r : be_c) + layer * 256;
    const int c0 = (tid & 7) * 32;
    const int h = pos >> lv.lwW, w = pos & (lv.W - 1);
    const int pp = (h + 1) * lv.P2W + (w + 1);
    unsigned short* p = x + (size_t)br * XELs + (size_t)lv.xo +
                        (size_t)n * lv.PP * 256 +
                        (size_t)(tid & 7) * lv.PP * 32 + (size_t)pp * 32;
    const float inv = 1.0f / (16.0f * (float)lv.HW);
    const int sb = ((slot * 5 + L) * 32 + n * 16) * 2;

    float scv[32], shv[32];
#pragma unroll
    for (int gg = 0; gg < 2; ++gg) {
        const int g = (c0 >> 4) + gg;
        const float mm = stats[sb + g * 2 + 0] * inv;
        const float v = stats[sb + g * 2 + 1] * inv - mm * mm;
        const float rs = rsqrtf(v + GN_EPS);
#pragma unroll
        for (int k = 0; k < 16; ++k) {
            const int c = g * 16 + k;
            const float sc = rs * gamma[c];
            scv[gg * 16 + k] = sc;
            shv[gg * 16 + k] = beta[c] - mm * sc;
        }
    }
#pragma unroll
    for (int u = 0; u < 4; ++u) {
        uint4 a = *(const uint4*)(p + u * 8);
        unsigned wds[4] = {a.x, a.y, a.z, a.w};
#pragma unroll
        for (int k = 0; k < 4; ++k) {
            const int e = u * 8 + k * 2;
            float lo = bf2f((unsigned short)(wds[k] & 0xffffu));
            float hi = bf2f((unsigned short)(wds[k] >> 16));
            lo = fmaxf(lo * scv[e]     + shv[e],     0.f);
            hi = fmaxf(hi * scv[e + 1] + shv[e + 1], 0.f);
            wds[k] = (unsigned)f2bf(lo) | ((unsigned)f2bf(hi) << 16);
        }
        uint4 o; o.x = wds[0]; o.y = wds[1]; o.z = wds[2]; o.w = wds[3];
        *(uint4*)(p + u * 8) = o;
    }
}

// ---------------------------------------------------------------------------
// fp32 NCHW feats -> bf16 ci-blocked padded interior.
// ---------------------------------------------------------------------------
__global__ __launch_bounds__(256) void prepx_k(
    const float* f0, const float* f1, const float* f2, const float* f3,
    const float* f4, unsigned short* __restrict__ xo, Tab tb)
{
    const float* fs[5] = {f0, f1, f2, f3, f4};
    const int tid = threadIdx.x, bx = blockIdx.x, n = blockIdx.z;
    int L = 0;
    while (L < 4 && bx >= tb.lv[L + 1].t_prep) ++L;
    const Lv lv = tb.lv[L];
    const int pos = (bx - lv.t_prep) * 64 + (tid & 63);
    const int wave = tid >> 6;
    if (pos >= lv.HW) return;
    const int h = pos >> lv.lwW, w = pos & (lv.W - 1);
    const int pp = (h + 1) * lv.P2W + (w + 1);
    const float* src = fs[L] + (size_t)n * 256 * lv.HW + pos;
    unsigned short* dst = xo + (size_t)lv.xo + (size_t)n * lv.PP * 256;
#pragma unroll
    for (int k = 0; k < 16; ++k) {
        const int c = wave * 64 + k * 4;
        ushort4 pk;
        pk.x = f2bf(src[(size_t)(c + 0) * lv.HW]);
        pk.y = f2bf(src[(size_t)(c + 1) * lv.HW]);
        pk.z = f2bf(src[(size_t)(c + 2) * lv.HW]);
        pk.w = f2bf(src[(size_t)(c + 3) * lv.HW]);
        *(ushort4*)(dst + (size_t)(c >> 5) * lv.PP * 32 +
                    (size_t)pp * 32 + (c & 31)) = pk;
    }
}

// ---------------------------------------------------------------------------
// tower weights: [br][layer][tap][kb][co 256][32ci] (per-step tile contiguous)
__global__ __launch_bounds__(256) void prepwt_k(
    const float* __restrict__ cw, const float* __restrict__ rw,
    unsigned short* __restrict__ dst)
{
    const int idx = blockIdx.x * 256 + threadIdx.x;   // 54*65536
    const int ci = idx & 255, co = (idx >> 8) & 255, r = idx >> 16;
    const int tap = r % 9, layer = (r / 9) % 3, br = r / 27;
    const float* s = br ? rw : cw;
    dst[(size_t)r * 65536 + (size_t)(((ci >> 5) * 256 + co) * 32) + (ci & 31)] =
        f2bf(s[(((size_t)layer * 256 + co) * 256 + ci) * 9 + tap]);
}

// head weights: [tap][kb][co rows][32ci]
__global__ __launch_bounds__(256) void prepwh_k(
    const float* __restrict__ src, unsigned short* __restrict__ dst,
    int CO, int rows, int roff)
{
    const int idx = blockIdx.x * 256 + threadIdx.x;
    if (idx >= CO * 2304) return;
    const int ci = idx & 255, rr = idx >> 8;
    const int tap = rr % 9, co = rr / 9;
    dst[((size_t)(tap * 8 + (ci >> 5)) * rows + roff + co) * 32 + (ci & 31)] =
        f2bf(src[((size_t)co * 256 + ci) * 9 + tap]);
}

// ---------------------------------------------------------------------------
extern "C" void kernel_launch(void* const* d_in, const int* in_sizes, int n_in,
                              void* d_out, int out_size, void* d_ws, size_t ws_size,
                              hipStream_t stream) {
    const float* f0 = (const float*)d_in[0];
    const float* f1 = (const float*)d_in[1];
    const float* f2 = (const float*)d_in[2];
    const float* f3 = (const float*)d_in[3];
    const float* f4 = (const float*)d_in[4];
    const float* cls_w  = (const float*)d_in[5];
    const float* cls_b  = (const float*)d_in[6];
    const float* cls_g  = (const float*)d_in[7];
    const float* cls_be = (const float*)d_in[8];
    const float* log_w  = (const float*)d_in[9];
    const float* log_b  = (const float*)d_in[10];
    const float* reg_w  = (const float*)d_in[11];
    const float* reg_b  = (const float*)d_in[12];
    const float* reg_g  = (const float*)d_in[13];
    const float* reg_be = (const float*)d_in[14];
    const float* bbox_w = (const float*)d_in[15];
    const float* bbox_b = (const float*)d_in[16];
    const float* ctr_w  = (const float*)d_in[17];
    const float* ctr_b  = (const float*)d_in[18];
    float* out = (float*)d_out;

    Tab tb;
    // t_conv: 128-pos tiles over PADDED pp space: ceil(PP/128) =
    // 104,27,8,3,1 -> cum 0,104,131,139,142 (NT=143; same as r0-r4).
    //            t_conv t_gn t_prep t_h5 xo       P2W  PP     HW     W    H   lwW loff
    tb.lv[0] = {   0,    0,    0,    0,   0,       130, 13260, 12800, 128, 100, 7, 0     };
    tb.lv[1] = { 104,  400,  200,  52,  6789120,    66,  3432,  3200,  64,  50, 6, 12800 };
    tb.lv[2] = { 131,  500,  250,  66,  8546304,    34,   918,   800,  32,  25, 5, 16000 };
    tb.lv[3] = { 139,  525,  263,  70,  9016320,    18,   270,   208,  16,  13, 4, 16800 };
    tb.lv[4] = { 142,  532,  267,  72,  9154560,    10,    90,    56,   8,   7, 3, 17008 };
    const int NT_CONV = 143, NT_GN = 534, NT_PREP = 268, NT_H5 = 73;
    const size_t XEL = 9200640;

    char* base = (char*)d_ws;
    size_t o = 0;
    auto take = [&](size_t bytes) {
        char* p = base + o; o += (bytes + 255) & ~(size_t)255; return p;
    };
    take(131072);                                        // guard 128KB
    unsigned short* PX = (unsigned short*)take(XEL * 2);          // shared input
    take(131072);
    unsigned short* B1 = (unsigned short*)take(XEL * 2 * 2);      // [br]
    take(131072);
    unsigned short* B2 = (unsigned short*)take(XEL * 2 * 2);      // [br]
    take(131072);
    unsigned short* WT  = (unsigned short*)take((size_t)54 * 65536 * 2);
    unsigned short* WHC = (unsigned short*)take((size_t)72 * 256 * 32 * 2); // 256-row padded
    unsigned short* WHR = (unsigned short*)take((size_t)9 * 16 * 256 * 2);
    float* ST  = (float*)take(1920 * 4);
    float* RB5 = (float*)take(32);

    hipMemsetAsync(PX, 0, XEL * 2, stream);
    hipMemsetAsync(B1, 0, XEL * 4, stream);
    hipMemsetAsync(B2, 0, XEL * 4, stream);
    hipMemsetAsync(ST, 0, 1920 * 4, stream);
    hipMemsetAsync(WHC, 0, (size_t)72 * 256 * 32 * 2, stream);
    hipMemsetAsync(WHR, 0, (size_t)9 * 16 * 256 * 2, stream);
    hipMemcpyAsync(RB5,     bbox_b, 4 * 4, hipMemcpyDeviceToDevice, stream);
    hipMemcpyAsync(RB5 + 4, ctr_b,  1 * 4, hipMemcpyDeviceToDevice, stream);

    prepwt_k<<<dim3(13824), dim3(256), 0, stream>>>(cls_w, reg_w, WT);
    prepwh_k<<<dim3(720), dim3(256), 0, stream>>>(log_w,  WHC, 80, 256, 0);
    prepwh_k<<<dim3(36),  dim3(256), 0, stream>>>(bbox_w, WHR, 4, 16, 0);
    prepwh_k<<<dim3(9),   dim3(256), 0, stream>>>(ctr_w,  WHR, 1, 16, 4);

    prepx_k<<<dim3(NT_PREP, 1, 2), dim3(256), 0, stream>>>(f0, f1, f2, f3, f4, PX, tb);

    // chain: conv0 PX->B1[br], gn0 B1; conv1 B1->B2, gn1 B2; conv2 B2->B1,
    // gn2 B1; cls-head B1[0]; reg-head5 B1[1].
    const size_t WBRS = (size_t)27 * 65536;
    unsigned short* cin[3]  = {PX, B1, B2};
    size_t          cbrs[3] = {0, XEL, XEL};
    unsigned short* cout_[3] = {B1, B2, B1};
    for (int i = 0; i < 3; ++i) {
        conv_k<0><<<dim3(NT_CONV, 1, 4), dim3(512), 0, stream>>>(
            cin[i], cbrs[i], WT + (size_t)i * 9 * 65536, WBRS, 256,
            cls_b + i * 256, reg_b + i * 256,
            cout_[i], ST, i, nullptr, 0, 0, 0, tb);
        gn_k<<<dim3(NT_GN, 1, 4), dim3(256), 0, stream>>>(
            cout_[i], ST, i, cls_g, cls_be, reg_g, reg_be, tb);
    }
    conv_k<1><<<dim3(NT_CONV, 1, 2), dim3(512), 0, stream>>>(
        B1, 0, WHC, 0, 256, log_b, log_b,
        nullptr, nullptr, 0, out, NCLS, 0, 0, tb);
    head5_k<<<dim3(NT_H5, 1, 2), dim3(256), 0, stream>>>(
        B1 + XEL, WHR, RB5, out, tb);
}

// Round 8
// 917.070 us; speedup vs baseline: 1.3243x; 1.1276x over previous
//
#include <hip/hip_runtime.h>

#define NCLS 80
#define TPOINTS 17064
#define GN_EPS 1e-5f

typedef float v4f __attribute__((ext_vector_type(4)));
typedef short v8s __attribute__((ext_vector_type(8)));

__device__ __forceinline__ unsigned short f2bf(float f) {
    unsigned u = __float_as_uint(f);
    unsigned r = (u + 0x7FFFu + ((u >> 16) & 1u)) >> 16;
    return (unsigned short)r;
}
__device__ __forceinline__ float bf2f(unsigned short h) {
    return __uint_as_float(((unsigned)h) << 16);
}
__device__ __forceinline__ void gload16(const unsigned short* g, unsigned short* l) {
    __builtin_amdgcn_global_load_lds(
        (const __attribute__((address_space(1))) unsigned int*)g,
        (__attribute__((address_space(3))) unsigned int*)l, 16, 0, 0);
}
template<int N> __device__ __forceinline__ void vwait() {
    asm volatile("s_waitcnt vmcnt(%0)" :: "n"(N) : "memory");
    __builtin_amdgcn_sched_barrier(0);
}
#define LGKM0 do { asm volatile("s_waitcnt lgkmcnt(0)" ::: "memory"); \
                   __builtin_amdgcn_sched_barrier(0); } while (0)

struct Lv { int t_conv, t_gn, t_prep, t_h5, xo, P2W, PP, HW, W, H, lwW, loff; };
struct Tab { Lv lv[5]; };

// ---------------------------------------------------------------------------
// Implicit-GEMM conv, 8-wave deep-pipeline structure at 2 BLOCKS/CU (r7:
// towers 236->205us, MfmaUtil 17%, occ 30%). r7 profile: head5_k was the
// LARGEST dispatch (233us, MfmaUtil 0.04%, 146 blocks, serial per-step
// sync loop) for 786 MFLOP of work. r8: DELETE head5_k; fold the reg-head
// (bbox+ctr, CO=5) into the pipelined HEAD=1 conv as z=2,3: br=0 -> cls
// logits from B1[0] (cols 0-79), br=1 -> bbox+ctr from B1[1] (cols 80-84,
// ReLU first 4) via a 2nd 256-row weight plane (rows 0-4 live, rest
// zeroed; co<CO guard drops dead cols). Head conv was underfilled at z=2
// (286/572 slots) so z=4 is ~free.
// Structure per r7: tile 256co x 128pos, 8 waves (4co x 2pos, 64x64,
// acc[4][4]); 3-deep pipeline; LDS 3*(16KB A + 8KB B)=72KB -> 2 blocks/CU;
// per half: 3 gloads/wave staged 2 ahead; vwait(6) -> barrier -> 8
// ds_read_b128 -> lgkmcnt(0) -> barrier -> stage h+3 -> setprio + 16 MFMA.
// XOR chunk-swizzle deposit/read (0 bank conflicts measured).
// TOWER (HEAD=0): bf16 ci-blocked out + fused GN stats. HEAD=1: fp32 out.
// ---------------------------------------------------------------------------
template<int HEAD>
__global__ __launch_bounds__(512, 4) void conv_k(
    const unsigned short* __restrict__ xin, size_t xin_brs,
    const unsigned short* __restrict__ wt, size_t wt_brs, int wrows,
    const float* __restrict__ bias_c, const float* __restrict__ bias_r,
    unsigned short* __restrict__ yout, float* __restrict__ stats, int layer,
    float* __restrict__ out,
    Tab tb)
{
    __shared__ __align__(16) unsigned short sA[3 * 256 * 32];   // 48KB
    __shared__ __align__(16) unsigned short sB[3 * 128 * 32];   // 24KB
    const int tid = threadIdx.x, lane = tid & 63, wave = tid >> 6;
    const int bx = blockIdx.x, z = blockIdx.z;
    const int n = z & 1, br = z >> 1;
    int L = 0;
    while (L < 4 && bx >= tb.lv[L + 1].t_conv) ++L;
    const Lv lv = tb.lv[L];
    const int pp0 = (bx - lv.t_conv) * 128;
    const size_t XELs = 9200640;
    const size_t PP32 = (size_t)lv.PP * 32;

    v4f acc[4][4];
#pragma unroll
    for (int i = 0; i < 4; ++i)
#pragma unroll
        for (int j = 0; j < 4; ++j) acc[i][j] = (v4f)0.f;

    const unsigned short* wtb = wt + (size_t)br * wt_brs;
    const float* bias = br ? bias_r : bias_c;
    const unsigned short* xb = xin + (size_t)br * xin_brs +
                               (size_t)lv.xo + (size_t)n * lv.PP * 256;

    // staging: A: wave w rows [w*32, +32) of 256; B: wave w rows [w*16, +16)
    // of 128. lane l -> row += l>>2, source chunk (l&3)^((l>>3)&3) (LDS holds
    // row-XOR-swizzled chunks; == chunk ^ ((row>>1)&3) for 16-row groups).
    const int lr = lane >> 2;
    const int lc = ((lane & 3) ^ ((lane >> 3) & 3)) * 8;
    const unsigned short* ag = wtb + (size_t)(wave * 32 + lr) * 32 + lc;
    const unsigned short* bgh = xb + (ptrdiff_t)(pp0 + wave * 16 + lr) * 32 + lc;
    unsigned short* laW = &sA[wave * 32 * 32];
    unsigned short* lbW = &sB[wave * 16 * 32];
    const size_t wstride2 = (size_t)wrows * 32;   // elems per K-half A tile

    const int col = lane & 15, q = lane >> 4;
    const int wr = wave & 3, wc = wave >> 2;      // 4 co-blocks x 2 pos-blocks
    const int qs = (q ^ ((col >> 1) & 3)) << 3;
    int ard[4], brd[4];
#pragma unroll
    for (int i = 0; i < 4; ++i) ard[i] = (wr * 64 + i * 16 + col) * 32 + qs;
#pragma unroll
    for (int j = 0; j < 4; ++j) brd[j] = (wc * 64 + j * 16 + col) * 32 + qs;

    auto stageHalf = [&](int s) {
        const int slot = s % 3;
        const unsigned short* at = ag + (size_t)s * wstride2;
        gload16(at,       laW + slot * 8192);
        gload16(at + 512, laW + slot * 8192 + 512);
        const int t = s >> 3, kb = s & 7;
        const ptrdiff_t goff = ((ptrdiff_t)(t / 3) - 1) * lv.P2W + (t % 3) - 1;
        gload16(bgh + (size_t)kb * PP32 + goff * 32, lbW + slot * 4096);
    };

    auto half_body = [&](int h, bool dostage) {
        const int sa = (h % 3) * 8192, sb_ = (h % 3) * 4096;
        v8s af[4], bfr[4];
#pragma unroll
        for (int i = 0; i < 4; ++i) af[i]  = *(const v8s*)&sA[sa + ard[i]];
#pragma unroll
        for (int j = 0; j < 4; ++j) bfr[j] = *(const v8s*)&sB[sb_ + brd[j]];
        LGKM0;                                   // frags in regs
        __builtin_amdgcn_s_barrier();            // all waves done reading slot
        if (dostage) stageHalf(h + 3);           // safe: slot (h+3)%3 == h%3
        __builtin_amdgcn_sched_barrier(0);
        __builtin_amdgcn_s_setprio(1);
#pragma unroll
        for (int i = 0; i < 4; ++i)
#pragma unroll
            for (int j = 0; j < 4; ++j)
                acc[i][j] = __builtin_amdgcn_mfma_f32_16x16x32_bf16(
                    af[i], bfr[j], acc[i][j], 0, 0, 0);
        __builtin_amdgcn_s_setprio(0);
    };

    // prologue: halves 0,1,2 in flight (9 gloads/wave, 3 per half)
    stageHalf(0); stageHalf(1); stageHalf(2);
#pragma unroll 1
    for (int h = 0; h < 70; ++h) {
        vwait<6>();                          // own 3 of half h retired
        __builtin_amdgcn_s_barrier();        // all waves: half h complete
        half_body(h, h < 69);
    }
    vwait<3>(); __builtin_amdgcn_s_barrier(); half_body(70, false);
    vwait<0>(); __builtin_amdgcn_s_barrier(); half_body(71, false);

    if (!HEAD) {
        unsigned short* yb = yout + (size_t)br * XELs + (size_t)lv.xo +
                             (size_t)n * lv.PP * 256;
        const int slot = br * 3 + layer;
#pragma unroll
        for (int i = 0; i < 4; ++i) {
            const int cobase = wr * 64 + i * 16 + q * 4;
            const float4 b4 = *(const float4*)(bias + cobase);
            const size_t kbo = (size_t)(cobase >> 5) * PP32;
            const int cc = cobase & 31;
            float s = 0.f, ss = 0.f;
#pragma unroll
            for (int j = 0; j < 4; ++j) {
                const int pp = pp0 + wc * 64 + j * 16 + col;
                const unsigned h2 = (unsigned)pp / (unsigned)lv.P2W;
                const unsigned w2 = (unsigned)pp - h2 * lv.P2W;
                const bool in = (h2 >= 1u) & (h2 <= (unsigned)lv.H) &
                                (w2 >= 1u) & (w2 <= (unsigned)lv.W);
                float v0 = acc[i][j][0] + b4.x;
                float v1 = acc[i][j][1] + b4.y;
                float v2 = acc[i][j][2] + b4.z;
                float v3 = acc[i][j][3] + b4.w;
                if (in) {
                    ushort4 pk;
                    pk.x = f2bf(v0); pk.y = f2bf(v1);
                    pk.z = f2bf(v2); pk.w = f2bf(v3);
                    *(ushort4*)(yb + kbo + (size_t)pp * 32 + cc) = pk;
                    s  += v0 + v1 + v2 + v3;
                    ss += v0 * v0 + v1 * v1 + v2 * v2 + v3 * v3;
                }
            }
#pragma unroll
            for (int o = 32; o > 0; o >>= 1) {
                s  += __shfl_down(s, o, 64);
                ss += __shfl_down(ss, o, 64);
            }
            if (lane == 0) {
                const int g = cobase >> 4;
                const int si = (((slot * 5 + L) * 32) + n * 16 + g) * 2;
                atomicAdd(&stats[si + 0], s);
                atomicAdd(&stats[si + 1], ss);
            }
        }
    } else {
        // br=0: cls logits from B1[0], CO=80, out cols 0..79, no relu.
        // br=1: bbox+ctr from B1[1], CO=5, out cols 80..84, relu co<4.
        const int CO_ = br ? 5 : 80;
        const int coo = br ? 80 : 0;
        const int rel = br ? 4 : 0;
#pragma unroll
        for (int i = 0; i < 4; ++i) {
            const int cobase = wr * 64 + i * 16 + q * 4;
            float bv[4];
#pragma unroll
            for (int k = 0; k < 4; ++k)
                bv[k] = (cobase + k < CO_) ? bias[cobase + k] : 0.f;
#pragma unroll
            for (int j = 0; j < 4; ++j) {
                const int pp = pp0 + wc * 64 + j * 16 + col;
                const unsigned h2 = (unsigned)pp / (unsigned)lv.P2W;
                const unsigned w2 = (unsigned)pp - h2 * lv.P2W;
                const bool in = (h2 >= 1u) & (h2 <= (unsigned)lv.H) &
                                (w2 >= 1u) & (w2 <= (unsigned)lv.W);
                if (in) {
                    const int p = (h2 - 1) * lv.W + (w2 - 1);
                    float* ob = out + ((size_t)n * TPOINTS + lv.loff + p) * 85 + coo;
#pragma unroll
                    for (int k = 0; k < 4; ++k) {
                        const int co = cobase + k;
                        if (co < CO_) {
                            float v = acc[i][j][k] + bv[k];
                            if (co < rel) v = fmaxf(v, 0.f);
                            ob[co] = v;
                        }
                    }
                }
            }
        }
    }
}

// ---------------------------------------------------------------------------
// GN + affine + ReLU, in-place, fused across levels AND branches (z=br*2+n).
// ---------------------------------------------------------------------------
__global__ __launch_bounds__(256) void gn_k(
    unsigned short* __restrict__ x, const float* __restrict__ stats, int layer,
    const float* __restrict__ g_c, const float* __restrict__ be_c,
    const float* __restrict__ g_r, const float* __restrict__ be_r, Tab tb)
{
    const int tid = threadIdx.x, bx = blockIdx.x, z = blockIdx.z;
    const int n = z & 1, br = z >> 1;
    const size_t XELs = 9200640;
    int L = 0;
    while (L < 4 && bx >= tb.lv[L + 1].t_gn) ++L;
    const Lv lv = tb.lv[L];
    const int pos = (bx - lv.t_gn) * 32 + (tid >> 3);
    if (pos >= lv.HW) return;
    const int slot = br * 3 + layer;
    const float* gamma = (br ? g_r : g_c) + layer * 256;
    const float* beta  = (br ? be_r : be_c) + layer * 256;
    const int c0 = (tid & 7) * 32;
    const int h = pos >> lv.lwW, w = pos & (lv.W - 1);
    const int pp = (h + 1) * lv.P2W + (w + 1);
    unsigned short* p = x + (size_t)br * XELs + (size_t)lv.xo +
                        (size_t)n * lv.PP * 256 +
                        (size_t)(tid & 7) * lv.PP * 32 + (size_t)pp * 32;
    const float inv = 1.0f / (16.0f * (float)lv.HW);
    const int sb = ((slot * 5 + L) * 32 + n * 16) * 2;

    float scv[32], shv[32];
#pragma unroll
    for (int gg = 0; gg < 2; ++gg) {
        const int g = (c0 >> 4) + gg;
        const float mm = stats[sb + g * 2 + 0] * inv;
        const float v = stats[sb + g * 2 + 1] * inv - mm * mm;
        const float rs = rsqrtf(v + GN_EPS);
#pragma unroll
        for (int k = 0; k < 16; ++k) {
            const int c = g * 16 + k;
            const float sc = rs * gamma[c];
            scv[gg * 16 + k] = sc;
            shv[gg * 16 + k] = beta[c] - mm * sc;
        }
    }
#pragma unroll
    for (int u = 0; u < 4; ++u) {
        uint4 a = *(const uint4*)(p + u * 8);
        unsigned wds[4] = {a.x, a.y, a.z, a.w};
#pragma unroll
        for (int k = 0; k < 4; ++k) {
            const int e = u * 8 + k * 2;
            float lo = bf2f((unsigned short)(wds[k] & 0xffffu));
            float hi = bf2f((unsigned short)(wds[k] >> 16));
            lo = fmaxf(lo * scv[e]     + shv[e],     0.f);
            hi = fmaxf(hi * scv[e + 1] + shv[e + 1], 0.f);
            wds[k] = (unsigned)f2bf(lo) | ((unsigned)f2bf(hi) << 16);
        }
        uint4 o; o.x = wds[0]; o.y = wds[1]; o.z = wds[2]; o.w = wds[3];
        *(uint4*)(p + u * 8) = o;
    }
}

// ---------------------------------------------------------------------------
// fp32 NCHW feats -> bf16 ci-blocked padded interior.
// ---------------------------------------------------------------------------
__global__ __launch_bounds__(256) void prepx_k(
    const float* f0, const float* f1, const float* f2, const float* f3,
    const float* f4, unsigned short* __restrict__ xo, Tab tb)
{
    const float* fs[5] = {f0, f1, f2, f3, f4};
    const int tid = threadIdx.x, bx = blockIdx.x, n = blockIdx.z;
    int L = 0;
    while (L < 4 && bx >= tb.lv[L + 1].t_prep) ++L;
    const Lv lv = tb.lv[L];
    const int pos = (bx - lv.t_prep) * 64 + (tid & 63);
    const int wave = tid >> 6;
    if (pos >= lv.HW) return;
    const int h = pos >> lv.lwW, w = pos & (lv.W - 1);
    const int pp = (h + 1) * lv.P2W + (w + 1);
    const float* src = fs[L] + (size_t)n * 256 * lv.HW + pos;
    unsigned short* dst = xo + (size_t)lv.xo + (size_t)n * lv.PP * 256;
#pragma unroll
    for (int k = 0; k < 16; ++k) {
        const int c = wave * 64 + k * 4;
        ushort4 pk;
        pk.x = f2bf(src[(size_t)(c + 0) * lv.HW]);
        pk.y = f2bf(src[(size_t)(c + 1) * lv.HW]);
        pk.z = f2bf(src[(size_t)(c + 2) * lv.HW]);
        pk.w = f2bf(src[(size_t)(c + 3) * lv.HW]);
        *(ushort4*)(dst + (size_t)(c >> 5) * lv.PP * 32 +
                    (size_t)pp * 32 + (c & 31)) = pk;
    }
}

// ---------------------------------------------------------------------------
// tower weights: [br][layer][tap][kb][co 256][32ci] (per-step tile contiguous)
__global__ __launch_bounds__(256) void prepwt_k(
    const float* __restrict__ cw, const float* __restrict__ rw,
    unsigned short* __restrict__ dst)
{
    const int idx = blockIdx.x * 256 + threadIdx.x;   // 54*65536
    const int ci = idx & 255, co = (idx >> 8) & 255, r = idx >> 16;
    const int tap = r % 9, layer = (r / 9) % 3, br = r / 27;
    const float* s = br ? rw : cw;
    dst[(size_t)r * 65536 + (size_t)(((ci >> 5) * 256 + co) * 32) + (ci & 31)] =
        f2bf(s[(((size_t)layer * 256 + co) * 256 + ci) * 9 + tap]);
}

// head weights: [tap][kb][co rows][32ci], rows=256 (zero-padded planes)
__global__ __launch_bounds__(256) void prepwh_k(
    const float* __restrict__ src, unsigned short* __restrict__ dst,
    int CO, int rows, int roff)
{
    const int idx = blockIdx.x * 256 + threadIdx.x;
    if (idx >= CO * 2304) return;
    const int ci = idx & 255, rr = idx >> 8;
    const int tap = rr % 9, co = rr / 9;
    dst[((size_t)(tap * 8 + (ci >> 5)) * rows + roff + co) * 32 + (ci & 31)] =
        f2bf(src[((size_t)co * 256 + ci) * 9 + tap]);
}

// ---------------------------------------------------------------------------
extern "C" void kernel_launch(void* const* d_in, const int* in_sizes, int n_in,
                              void* d_out, int out_size, void* d_ws, size_t ws_size,
                              hipStream_t stream) {
    const float* f0 = (const float*)d_in[0];
    const float* f1 = (const float*)d_in[1];
    const float* f2 = (const float*)d_in[2];
    const float* f3 = (const float*)d_in[3];
    const float* f4 = (const float*)d_in[4];
    const float* cls_w  = (const float*)d_in[5];
    const float* cls_b  = (const float*)d_in[6];
    const float* cls_g  = (const float*)d_in[7];
    const float* cls_be = (const float*)d_in[8];
    const float* log_w  = (const float*)d_in[9];
    const float* log_b  = (const float*)d_in[10];
    const float* reg_w  = (const float*)d_in[11];
    const float* reg_b  = (const float*)d_in[12];
    const float* reg_g  = (const float*)d_in[13];
    const float* reg_be = (const float*)d_in[14];
    const float* bbox_w = (const float*)d_in[15];
    const float* bbox_b = (const float*)d_in[16];
    const float* ctr_w  = (const float*)d_in[17];
    const float* ctr_b  = (const float*)d_in[18];
    float* out = (float*)d_out;

    Tab tb;
    // t_conv: 128-pos tiles over PADDED pp space: ceil(PP/128) =
    // 104,27,8,3,1 -> cum 0,104,131,139,142 (NT=143).
    //            t_conv t_gn t_prep t_h5 xo       P2W  PP     HW     W    H   lwW loff
    tb.lv[0] = {   0,    0,    0,    0,   0,       130, 13260, 12800, 128, 100, 7, 0     };
    tb.lv[1] = { 104,  400,  200,  52,  6789120,    66,  3432,  3200,  64,  50, 6, 12800 };
    tb.lv[2] = { 131,  500,  250,  66,  8546304,    34,   918,   800,  32,  25, 5, 16000 };
    tb.lv[3] = { 139,  525,  263,  70,  9016320,    18,   270,   208,  16,  13, 4, 16800 };
    tb.lv[4] = { 142,  532,  267,  72,  9154560,    10,    90,    56,   8,   7, 3, 17008 };
    const int NT_CONV = 143, NT_GN = 534, NT_PREP = 268;
    const size_t XEL = 9200640;
    const size_t WHP = (size_t)72 * 256 * 32;     // one 256-row head weight plane

    char* base = (char*)d_ws;
    size_t o = 0;
    auto take = [&](size_t bytes) {
        char* p = base + o; o += (bytes + 255) & ~(size_t)255; return p;
    };
    take(131072);                                        // guard 128KB
    unsigned short* PX = (unsigned short*)take(XEL * 2);          // shared input
    take(131072);
    unsigned short* B1 = (unsigned short*)take(XEL * 2 * 2);      // [br]
    take(131072);
    unsigned short* B2 = (unsigned short*)take(XEL * 2 * 2);      // [br]
    take(131072);
    unsigned short* WT = (unsigned short*)take((size_t)54 * 65536 * 2);
    unsigned short* WH = (unsigned short*)take(WHP * 2 * 2);      // [br] planes
    float* ST  = (float*)take(1920 * 4);
    float* RB5 = (float*)take(32);

    hipMemsetAsync(PX, 0, XEL * 2, stream);
    hipMemsetAsync(B1, 0, XEL * 4, stream);
    hipMemsetAsync(B2, 0, XEL * 4, stream);
    hipMemsetAsync(ST, 0, 1920 * 4, stream);
    hipMemsetAsync(WH, 0, WHP * 2 * 2, stream);
    hipMemcpyAsync(RB5,     bbox_b, 4 * 4, hipMemcpyDeviceToDevice, stream);
    hipMemcpyAsync(RB5 + 4, ctr_b,  1 * 4, hipMemcpyDeviceToDevice, stream);

    prepwt_k<<<dim3(13824), dim3(256), 0, stream>>>(cls_w, reg_w, WT);
    prepwh_k<<<dim3(720), dim3(256), 0, stream>>>(log_w,  WH,       80, 256, 0);
    prepwh_k<<<dim3(36),  dim3(256), 0, stream>>>(bbox_w, WH + WHP,  4, 256, 0);
    prepwh_k<<<dim3(9),   dim3(256), 0, stream>>>(ctr_w,  WH + WHP,  1, 256, 4);

    prepx_k<<<dim3(NT_PREP, 1, 2), dim3(256), 0, stream>>>(f0, f1, f2, f3, f4, PX, tb);

    // chain: conv0 PX->B1[br], gn0 B1; conv1 B1->B2, gn1 B2; conv2 B2->B1,
    // gn2 B1; fused head (z=4): br=0 cls from B1[0], br=1 bbox+ctr from B1[1].
    const size_t WBRS = (size_t)27 * 65536;
    unsigned short* cin[3]  = {PX, B1, B2};
    size_t          cbrs[3] = {0, XEL, XEL};
    unsigned short* cout_[3] = {B1, B2, B1};
    for (int i = 0; i < 3; ++i) {
        conv_k<0><<<dim3(NT_CONV, 1, 4), dim3(512), 0, stream>>>(
            cin[i], cbrs[i], WT + (size_t)i * 9 * 65536, WBRS, 256,
            cls_b + i * 256, reg_b + i * 256,
            cout_[i], ST, i, nullptr, tb);
        gn_k<<<dim3(NT_GN, 1, 4), dim3(256), 0, stream>>>(
            cout_[i], ST, i, cls_g, cls_be, reg_g, reg_be, tb);
    }
    conv_k<1><<<dim3(NT_CONV, 1, 4), dim3(512), 0, stream>>>(
        B1, XEL, WH, WHP, 256, log_b, RB5,
        nullptr, nullptr, 0, out, tb);
}